// Round 6
// baseline (188.859 us; speedup 1.0000x reference)
//
#include <hip/hip_runtime.h>
#include <math.h>

#define N_NODES 50000
#define DEG 16
#define EPSF 1e-5f

typedef unsigned int uint;
typedef unsigned short ushort;

using bf16x8 = __attribute__((ext_vector_type(8))) short;
using f32x4  = __attribute__((ext_vector_type(4))) float;

__device__ __forceinline__ float bf2f_lo(uint u) { return __uint_as_float(u << 16); }
__device__ __forceinline__ float bf2f_hi(uint u) { return __uint_as_float(u & 0xFFFF0000u); }
__device__ __forceinline__ uint  f2bf_rn(float f) {
    uint u = __float_as_uint(f);
    return (u + 0x7FFFu + ((u >> 16) & 1u)) >> 16;
}
__device__ __forceinline__ uint pack2(float a, float b) {
    return f2bf_rn(a) | (f2bf_rn(b) << 16);
}

// ---- VALU-only wave reductions --------------------------------------------
__device__ __forceinline__ float pl32_sum(float v) {
#if __has_builtin(__builtin_amdgcn_permlane32_swap)
    auto r = __builtin_amdgcn_permlane32_swap((int)__float_as_uint(v), (int)__float_as_uint(v), false, false);
    return __uint_as_float((uint)r[0]) + __uint_as_float((uint)r[1]);
#else
    return v + __shfl_xor(v, 32, 64);
#endif
}
__device__ __forceinline__ float pl16_sum(float v) {
#if __has_builtin(__builtin_amdgcn_permlane16_swap)
    auto r = __builtin_amdgcn_permlane16_swap((int)__float_as_uint(v), (int)__float_as_uint(v), false, false);
    return __uint_as_float((uint)r[0]) + __uint_as_float((uint)r[1]);
#else
    return v + __shfl_xor(v, 16, 64);
#endif
}
#define DPP_ROR_ADD(v, CTRL) \
    v += __uint_as_float((uint)__builtin_amdgcn_update_dpp(0, (int)__float_as_uint(v), (CTRL), 0xF, 0xF, false))

// sum over each 32-lane half
__device__ __forceinline__ float red32(float v) {
    DPP_ROR_ADD(v, 0x121);
    DPP_ROR_ADD(v, 0x122);
    DPP_ROR_ADD(v, 0x124);
    DPP_ROR_ADD(v, 0x128);
    return pl16_sum(v);
}

// ---- fast hyperbolic helpers ----------------------------------------------
__device__ __forceinline__ float tanh_over_x(float nm) {      // tanh(nm)/nm, nm>0
    float e = __expf(2.f * nm);
    float t = 1.f - __fdividef(2.f, e + 1.f);
    return __fdividef(t, nm);
}
__device__ __forceinline__ float atanh_over_x(float n) {      // atanh(n)/n, 0<n<1
    float l = __logf(__fdividef(1.f + n, 1.f - n));
    return 0.5f * __fdividef(l, n);
}

// ---------------------------------------------------------------------------
// K0: weight prep: W_t[n][k] = bf16(W_in[k][n]), Wo_t[n][k] = bf16(W_out[k][n])
// ---------------------------------------------------------------------------
__global__ __launch_bounds__(256) void k_prep(
    const float* __restrict__ W_in, const float* __restrict__ W_out,
    ushort* __restrict__ W_t, ushort* __restrict__ Wo_t)
{
    const int b = blockIdx.x, t = threadIdx.x;
    if (b < 256) {
        W_t[b * 256 + t] = (ushort)f2bf_rn(W_in[t * 256 + b]);
    } else {
        const int n = b - 256;
        Wo_t[n * 256 + t] = (ushort)f2bf_rn(W_out[t * 128 + n]);
    }
}

// ---------------------------------------------------------------------------
// K1: l1 = feat @ W_in + b_in  (bf16 MFMA, swapped operands).
// Output split into two half-dim tables l1a (cols 0..127), l1b (128..255).
// ---------------------------------------------------------------------------
__global__ __launch_bounds__(256) void k_encode_mfma(
    const int* __restrict__ x,
    const float* __restrict__ emb0, const float* __restrict__ emb1,
    const float* __restrict__ emb2,
    const ushort* __restrict__ W_t, const float* __restrict__ b_in,
    ushort* __restrict__ l1a, ushort* __restrict__ l1b)
{
    __shared__ ushort A[64 * 256];                  // 32 KB, swizzled
    const int t  = threadIdx.x;
    const int m0 = blockIdx.x * 64;

    #pragma unroll
    for (int it = 0; it < 2; ++it) {
        const int nl   = it * 32 + (t >> 3);
        const int seg  = t & 7;
        const int node = m0 + nl;
        const int k0   = seg * 32;
        const float* p;
        if (node < N_NODES) {
            if (seg < 3)      p = emb0 + (size_t)x[node * 3 + 0] * 96 + k0;
            else if (seg < 6) p = emb1 + (size_t)x[node * 3 + 1] * 96 + (k0 - 96);
            else              p = emb2 + (size_t)x[node * 3 + 2] * 64 + (k0 - 192);
        } else {
            p = emb0;
        }
        const uint base = (uint)(nl * 512 + seg * 64);
        const uint sw   = (uint)((nl & 7) << 4);
        #pragma unroll
        for (int u = 0; u < 4; ++u) {
            float4 v0 = *(const float4*)(p + u * 8);
            float4 v1 = *(const float4*)(p + u * 8 + 4);
            uint4 pk;
            pk.x = pack2(v0.x, v0.y); pk.y = pack2(v0.z, v0.w);
            pk.z = pack2(v1.x, v1.y); pk.w = pack2(v1.z, v1.w);
            *(uint4*)((char*)A + ((base + u * 16) ^ sw)) = pk;
        }
    }
    __syncthreads();

    const int lane = t & 63;
    const int w    = t >> 6;
    const int l15  = lane & 15;
    const int lhi  = lane >> 4;

    f32x4 acc[4][4];
    #pragma unroll
    for (int rf = 0; rf < 4; ++rf)
        #pragma unroll
        for (int nf = 0; nf < 4; ++nf)
            acc[rf][nf] = (f32x4){0.f, 0.f, 0.f, 0.f};

    const ushort* Wp = W_t + (size_t)(w * 64 + l15) * 256 + lhi * 8;
    const uint asw = (uint)((l15 & 7) << 4);

    for (int kk = 0; kk < 8; ++kk) {
        bf16x8 f[4];
        #pragma unroll
        for (int rf = 0; rf < 4; ++rf) {
            const uint ad = (uint)((rf * 16 + l15) * 512 + lhi * 16 + kk * 64);
            f[rf] = *(const bf16x8*)((const char*)A + (ad ^ asw));
        }
        #pragma unroll
        for (int nf = 0; nf < 4; ++nf) {
            bf16x8 wv = *(const bf16x8*)(Wp + (size_t)nf * 16 * 256 + kk * 32);
            #pragma unroll
            for (int rf = 0; rf < 4; ++rf)
                acc[rf][nf] = __builtin_amdgcn_mfma_f32_16x16x32_bf16(wv, f[rf], acc[rf][nf], 0, 0, 0);
        }
    }

    ushort* htbl = (w < 2) ? l1a : l1b;
    #pragma unroll
    for (int rf = 0; rf < 4; ++rf) {
        const int m = m0 + rf * 16 + l15;
        if (m < N_NODES) {
            #pragma unroll
            for (int nf = 0; nf < 4; ++nf) {
                const int n = w * 64 + nf * 16 + lhi * 4;      // 0..255
                float4 bb = *(const float4*)&b_in[n];
                uint2 pk;
                pk.x = pack2(acc[rf][nf][0] + bb.x, acc[rf][nf][1] + bb.y);
                pk.y = pack2(acc[rf][nf][2] + bb.z, acc[rf][nf][3] + bb.w);
                *(uint2*)&htbl[(size_t)m * 128 + (n & 127)] = pk;
            }
        }
    }
}

// ---------------------------------------------------------------------------
// KG: z_half[v] = mean_17 over {v} ∪ src[16v..16v+15] of tbl rows (256 B each).
// Wave per node; 4 groups of 16 lanes; group g fetches srcs {g,4+g,8+g,12+g},
// group 0 additionally fetches the self row. Cross-group reduce via permlane.
// Used for both hat layers (hat1 pre-norm z, hat2 identity z2).
// ---------------------------------------------------------------------------
__global__ __launch_bounds__(256) void k_gather_mean_half(
    const ushort* __restrict__ tbl, const int* __restrict__ src,
    ushort* __restrict__ zout)
{
    const int lane = threadIdx.x & 63;
    const int g    = lane >> 4;         // group 0..3
    const int pos  = lane & 15;         // 16B chunk within 256B row
    const int v    = blockIdx.x * 4 + (threadIdx.x >> 6);   // grid exact 12500*4
    const int vv   = __builtin_amdgcn_readfirstlane(v);

    const int* sp = src + (size_t)vv * DEG;

    uint4 r[4];
    #pragma unroll
    for (int j = 0; j < 4; j++) {
        int s = sp[j * 4 + g];
        r[j] = *(const uint4*)(tbl + ((size_t)s << 7) + pos * 8);
    }

    float acc[8];
    #pragma unroll
    for (int i = 0; i < 8; i++) acc[i] = 0.f;
    #pragma unroll
    for (int j = 0; j < 4; j++) {
        acc[0] += bf2f_lo(r[j].x); acc[1] += bf2f_hi(r[j].x);
        acc[2] += bf2f_lo(r[j].y); acc[3] += bf2f_hi(r[j].y);
        acc[4] += bf2f_lo(r[j].z); acc[5] += bf2f_hi(r[j].z);
        acc[6] += bf2f_lo(r[j].w); acc[7] += bf2f_hi(r[j].w);
    }
    if (g == 0) {   // self row
        uint4 rs = *(const uint4*)(tbl + ((size_t)vv << 7) + pos * 8);
        acc[0] += bf2f_lo(rs.x); acc[1] += bf2f_hi(rs.x);
        acc[2] += bf2f_lo(rs.y); acc[3] += bf2f_hi(rs.y);
        acc[4] += bf2f_lo(rs.z); acc[5] += bf2f_hi(rs.z);
        acc[6] += bf2f_lo(rs.w); acc[7] += bf2f_hi(rs.w);
    }
    // cross-group: sum the 4 groups (lane^16 and lane^32)
    #pragma unroll
    for (int i = 0; i < 8; i++) {
        acc[i] = pl16_sum(acc[i]);
        acc[i] = pl32_sum(acc[i]);
    }

    const float inv = 1.f / (float)(DEG + 1);
    if (g == 0) {
        uint4 o;
        o.x = pack2(acc[0] * inv, acc[1] * inv);
        o.y = pack2(acc[2] * inv, acc[3] * inv);
        o.z = pack2(acc[4] * inv, acc[5] * inv);
        o.w = pack2(acc[6] * inv, acc[7] * inv);
        *(uint4*)(zout + ((size_t)vv << 7) + pos * 8) = o;
    }
}

// ---------------------------------------------------------------------------
// KF: hat1 finalize: z (two bf16 half-tables) -> l2 = log0(relu(exp0(z)))
// Wave per node; lanes 0..31 handle half A, 32..63 half B (4 comps/lane).
// ---------------------------------------------------------------------------
__global__ __launch_bounds__(256) void k_hat1_fin(
    const ushort* __restrict__ za, const ushort* __restrict__ zb,
    ushort* __restrict__ l2a, ushort* __restrict__ l2b)
{
    const int lane = threadIdx.x & 63;
    const int half = lane >> 5;
    const int li   = lane & 31;
    const int v    = blockIdx.x * 4 + (threadIdx.x >> 6);
    const int vv   = __builtin_amdgcn_readfirstlane(v);

    const ushort* zp = half ? zb : za;
    uint2 u = *(const uint2*)(zp + ((size_t)vv << 7) + li * 4);

    float z[4];
    z[0] = bf2f_lo(u.x); z[1] = bf2f_hi(u.x);
    z[2] = bf2f_lo(u.y); z[3] = bf2f_hi(u.y);

    float rz[4], ss = 0.f, ssp = 0.f;
    #pragma unroll
    for (int i = 0; i < 4; i++) {
        ss += z[i] * z[i];
        rz[i] = fmaxf(z[i], 0.f);
        ssp += rz[i] * rz[i];
    }
    ss  = pl32_sum(red32(ss));
    ssp = pl32_sum(red32(ssp));

    float norm = sqrtf(ss);
    float nm = fmaxf(norm, EPSF);
    float se = tanh_over_x(nm);               // exp0 scale
    float nh = se * sqrtf(ssp);               // ||relu(exp0(z))||
    float nc = fminf(fmaxf(nh, EPSF), 1.f - EPSF);
    float c  = atanh_over_x(nc) * se;         // combined scale

    uint2 o;
    o.x = pack2(c * rz[0], c * rz[1]);
    o.y = pack2(c * rz[2], c * rz[3]);
    ushort* op = half ? l2b : l2a;
    *(uint2*)(op + ((size_t)vv << 7) + li * 4) = o;
}

// ---------------------------------------------------------------------------
// K4: out = exp0(z2 @ W_out + b_out)  (bf16 MFMA, swapped operands).
// z2 comes as two half-dim tables.
// ---------------------------------------------------------------------------
__global__ __launch_bounds__(256) void k_fc_out_mfma(
    const ushort* __restrict__ z2a, const ushort* __restrict__ z2b,
    const ushort* __restrict__ Wo_t,
    const float* __restrict__ b_out, float* __restrict__ out)
{
    const int t    = threadIdx.x;
    const int lane = t & 63;
    const int w    = t >> 6;
    const int l15  = lane & 15;
    const int lhi  = lane >> 4;
    const int m0   = blockIdx.x * 128;

    f32x4 acc[2][8];
    #pragma unroll
    for (int rf = 0; rf < 2; ++rf)
        #pragma unroll
        for (int nf = 0; nf < 8; ++nf)
            acc[rf][nf] = (f32x4){0.f, 0.f, 0.f, 0.f};

    const size_t arow = (size_t)(m0 + w * 32 + l15) * 128 + lhi * 8;
    const ushort* Aa = z2a + arow;
    const ushort* Ab = z2b + arow;
    const ushort* Wp = Wo_t + (size_t)l15 * 256 + lhi * 8;

    #pragma unroll
    for (int kk = 0; kk < 4; ++kk) {
        bf16x8 f0 = *(const bf16x8*)(Aa + kk * 32);
        bf16x8 f1 = *(const bf16x8*)(Aa + 16 * 128 + kk * 32);
        #pragma unroll
        for (int nf = 0; nf < 8; ++nf) {
            bf16x8 wv = *(const bf16x8*)(Wp + (size_t)nf * 16 * 256 + kk * 32);
            acc[0][nf] = __builtin_amdgcn_mfma_f32_16x16x32_bf16(wv, f0, acc[0][nf], 0, 0, 0);
            acc[1][nf] = __builtin_amdgcn_mfma_f32_16x16x32_bf16(wv, f1, acc[1][nf], 0, 0, 0);
        }
    }
    #pragma unroll
    for (int kk = 0; kk < 4; ++kk) {
        bf16x8 f0 = *(const bf16x8*)(Ab + kk * 32);
        bf16x8 f1 = *(const bf16x8*)(Ab + 16 * 128 + kk * 32);
        #pragma unroll
        for (int nf = 0; nf < 8; ++nf) {
            bf16x8 wv = *(const bf16x8*)(Wp + (size_t)nf * 16 * 256 + (kk + 4) * 32);
            acc[0][nf] = __builtin_amdgcn_mfma_f32_16x16x32_bf16(wv, f0, acc[0][nf], 0, 0, 0);
            acc[1][nf] = __builtin_amdgcn_mfma_f32_16x16x32_bf16(wv, f1, acc[1][nf], 0, 0, 0);
        }
    }

    float4 bb[8];
    #pragma unroll
    for (int nf = 0; nf < 8; ++nf)
        bb[nf] = *(const float4*)&b_out[nf * 16 + lhi * 4];

    #pragma unroll
    for (int rf = 0; rf < 2; ++rf) {
        const int m = m0 + w * 32 + rf * 16 + l15;
        float ss = 0.f;
        #pragma unroll
        for (int nf = 0; nf < 8; ++nf) {
            float t0 = acc[rf][nf][0] + bb[nf].x;
            float t1 = acc[rf][nf][1] + bb[nf].y;
            float t2 = acc[rf][nf][2] + bb[nf].z;
            float t3 = acc[rf][nf][3] + bb[nf].w;
            acc[rf][nf][0] = t0; acc[rf][nf][1] = t1;
            acc[rf][nf][2] = t2; acc[rf][nf][3] = t3;
            ss += t0 * t0 + t1 * t1 + t2 * t2 + t3 * t3;
        }
        ss = pl16_sum(ss);
        ss = pl32_sum(ss);
        float norm = sqrtf(ss);
        float nm = fmaxf(norm, EPSF);
        float se = tanh_over_x(nm);
        if (m < N_NODES) {
            #pragma unroll
            for (int nf = 0; nf < 8; ++nf) {
                float4 o;
                o.x = se * acc[rf][nf][0];
                o.y = se * acc[rf][nf][1];
                o.z = se * acc[rf][nf][2];
                o.w = se * acc[rf][nf][3];
                *(float4*)&out[(size_t)m * 128 + nf * 16 + lhi * 4] = o;
            }
        }
    }
}

extern "C" void kernel_launch(void* const* d_in, const int* in_sizes, int n_in,
                              void* d_out, int out_size, void* d_ws, size_t ws_size,
                              hipStream_t stream) {
    const int*   x     = (const int*)  d_in[0];
    const float* emb0  = (const float*)d_in[1];
    const float* emb1  = (const float*)d_in[2];
    const float* emb2  = (const float*)d_in[3];
    const float* W_in  = (const float*)d_in[4];
    const float* b_in  = (const float*)d_in[5];
    const float* W_out = (const float*)d_in[6];
    const float* b_out = (const float*)d_in[7];
    const int*   src0  = (const int*)  d_in[8];
    const int*   src1  = (const int*)  d_in[10];
    float* out = (float*)d_out;

    const size_t HT = (size_t)N_NODES * 128;   // ushorts per half-table (12.8 MB)
    ushort* l1a = (ushort*)d_ws;
    ushort* l1b = l1a + HT;
    ushort* l2a = l1b + HT;
    ushort* l2b = l2a + HT;
    ushort* za  = l2b + HT;       // hat1 z halves; reused as z2 halves
    ushort* zb  = za  + HT;
    ushort* W_t  = zb + HT;       // 128 KB
    ushort* Wo_t = W_t + 256 * 256;

    k_prep<<<384, 256, 0, stream>>>(W_in, W_out, W_t, Wo_t);
    k_encode_mfma<<<(N_NODES + 63) / 64, 256, 0, stream>>>(x, emb0, emb1, emb2, W_t, b_in, l1a, l1b);

    // hat layer 1: two half-dim gather passes + finalize
    k_gather_mean_half<<<N_NODES / 4, 256, 0, stream>>>(l1a, src0, za);
    k_gather_mean_half<<<N_NODES / 4, 256, 0, stream>>>(l1b, src0, zb);
    k_hat1_fin<<<N_NODES / 4, 256, 0, stream>>>(za, zb, l2a, l2b);

    // hat layer 2: identity output -> z2 halves directly
    k_gather_mean_half<<<N_NODES / 4, 256, 0, stream>>>(l2a, src1, za);
    k_gather_mean_half<<<N_NODES / 4, 256, 0, stream>>>(l2b, src1, zb);

    k_fc_out_mfma<<<(N_NODES + 127) / 128, 256, 0, stream>>>(za, zb, Wo_t, b_out, out);
}

// Round 7
// 149.966 us; speedup vs baseline: 1.2593x; 1.2593x over previous
//
#include <hip/hip_runtime.h>
#include <math.h>

#define N_NODES 50000
#define DEG 16
#define EPSF 1e-5f

typedef unsigned int uint;
typedef unsigned short ushort;
typedef unsigned char uchar;

using bf16x8 = __attribute__((ext_vector_type(8))) short;
using f32x4  = __attribute__((ext_vector_type(4))) float;

__device__ __forceinline__ uint f2bf_rn(float f) {
    uint u = __float_as_uint(f);
    return (u + 0x7FFFu + ((u >> 16) & 1u)) >> 16;
}
__device__ __forceinline__ uint pack2(float a, float b) {
    return f2bf_rn(a) | (f2bf_rn(b) << 16);
}

// ---- VALU-only wave reductions --------------------------------------------
__device__ __forceinline__ float pl32_sum(float v) {
#if __has_builtin(__builtin_amdgcn_permlane32_swap)
    auto r = __builtin_amdgcn_permlane32_swap((int)__float_as_uint(v), (int)__float_as_uint(v), false, false);
    return __uint_as_float((uint)r[0]) + __uint_as_float((uint)r[1]);
#else
    return v + __shfl_xor(v, 32, 64);
#endif
}
__device__ __forceinline__ float pl16_sum(float v) {
#if __has_builtin(__builtin_amdgcn_permlane16_swap)
    auto r = __builtin_amdgcn_permlane16_swap((int)__float_as_uint(v), (int)__float_as_uint(v), false, false);
    return __uint_as_float((uint)r[0]) + __uint_as_float((uint)r[1]);
#else
    return v + __shfl_xor(v, 16, 64);
#endif
}
__device__ __forceinline__ float pl32_max(float v) {
#if __has_builtin(__builtin_amdgcn_permlane32_swap)
    auto r = __builtin_amdgcn_permlane32_swap((int)__float_as_uint(v), (int)__float_as_uint(v), false, false);
    return fmaxf(__uint_as_float((uint)r[0]), __uint_as_float((uint)r[1]));
#else
    return fmaxf(v, __shfl_xor(v, 32, 64));
#endif
}
__device__ __forceinline__ float pl16_max(float v) {
#if __has_builtin(__builtin_amdgcn_permlane16_swap)
    auto r = __builtin_amdgcn_permlane16_swap((int)__float_as_uint(v), (int)__float_as_uint(v), false, false);
    return fmaxf(__uint_as_float((uint)r[0]), __uint_as_float((uint)r[1]));
#else
    return fmaxf(v, __shfl_xor(v, 16, 64));
#endif
}
#define DPP_ROR_ADD(v, CTRL) \
    v += __uint_as_float((uint)__builtin_amdgcn_update_dpp(0, (int)__float_as_uint(v), (CTRL), 0xF, 0xF, false))
#define DPP_ROR_MAX(v, CTRL) \
    v = fmaxf(v, __uint_as_float((uint)__builtin_amdgcn_update_dpp(0, (int)__float_as_uint(v), (CTRL), 0xF, 0xF, false)))

// full sum / max within each 16-lane DPP row
__device__ __forceinline__ float red16_sum(float v) {
    DPP_ROR_ADD(v, 0x121); DPP_ROR_ADD(v, 0x122);
    DPP_ROR_ADD(v, 0x124); DPP_ROR_ADD(v, 0x128);
    return v;
}
__device__ __forceinline__ float red16_max(float v) {
    DPP_ROR_MAX(v, 0x121); DPP_ROR_MAX(v, 0x122);
    DPP_ROR_MAX(v, 0x124); DPP_ROR_MAX(v, 0x128);
    return v;
}

// ---- fast hyperbolic helpers ----------------------------------------------
__device__ __forceinline__ float tanh_over_x(float nm) {      // tanh(nm)/nm, nm>0
    float e = __expf(2.f * nm);
    float t = 1.f - __fdividef(2.f, e + 1.f);
    return __fdividef(t, nm);
}
__device__ __forceinline__ float atanh_over_x(float n) {      // atanh(n)/n, 0<n<1
    float l = __logf(__fdividef(1.f + n, 1.f - n));
    return 0.5f * __fdividef(l, n);
}

// ---- int8 decode: 4 ubytes of dw, acc[i] += ubyte_i * rs ------------------
__device__ __forceinline__ void acc4(float* acc, uint dw, float rs) {
    acc[0] = fmaf((float)(dw & 0xffu),         rs, acc[0]);
    acc[1] = fmaf((float)((dw >> 8) & 0xffu),  rs, acc[1]);
    acc[2] = fmaf((float)((dw >> 16) & 0xffu), rs, acc[2]);
    acc[3] = fmaf((float)(dw >> 24),           rs, acc[3]);
}

// ---------------------------------------------------------------------------
// K0: weight prep: W_t[n][k] = bf16(W_in[k][n]), Wo_t[n][k] = bf16(W_out[k][n])
// ---------------------------------------------------------------------------
__global__ __launch_bounds__(256) void k_prep(
    const float* __restrict__ W_in, const float* __restrict__ W_out,
    ushort* __restrict__ W_t, ushort* __restrict__ Wo_t)
{
    const int b = blockIdx.x, t = threadIdx.x;
    if (b < 256) {
        W_t[b * 256 + t] = (ushort)f2bf_rn(W_in[t * 256 + b]);
    } else {
        const int n = b - 256;
        Wo_t[n * 256 + t] = (ushort)f2bf_rn(W_out[t * 128 + n]);
    }
}

// ---------------------------------------------------------------------------
// K1: t = feat @ W_in + b_in (bf16 MFMA, swapped operands); quantize rows to
// biased-u8 q1 (u = rint(v*127/rowmax)+128) + rscale1 = rowmax/127.
// ---------------------------------------------------------------------------
__global__ __launch_bounds__(256) void k_encode_mfma(
    const int* __restrict__ x,
    const float* __restrict__ emb0, const float* __restrict__ emb1,
    const float* __restrict__ emb2,
    const ushort* __restrict__ W_t, const float* __restrict__ b_in,
    uchar* __restrict__ q1, float* __restrict__ rscale1)
{
    __shared__ ushort A[64 * 256];                  // 32 KB, swizzled
    __shared__ float smax[4][64];
    const int t  = threadIdx.x;
    const int m0 = blockIdx.x * 64;

    #pragma unroll
    for (int it = 0; it < 2; ++it) {
        const int nl   = it * 32 + (t >> 3);
        const int seg  = t & 7;
        const int node = m0 + nl;
        const int k0   = seg * 32;
        const float* p;
        if (node < N_NODES) {
            if (seg < 3)      p = emb0 + (size_t)x[node * 3 + 0] * 96 + k0;
            else if (seg < 6) p = emb1 + (size_t)x[node * 3 + 1] * 96 + (k0 - 96);
            else              p = emb2 + (size_t)x[node * 3 + 2] * 64 + (k0 - 192);
        } else {
            p = emb0;
        }
        const uint base = (uint)(nl * 512 + seg * 64);
        const uint sw   = (uint)((nl & 7) << 4);
        #pragma unroll
        for (int u = 0; u < 4; ++u) {
            float4 v0 = *(const float4*)(p + u * 8);
            float4 v1 = *(const float4*)(p + u * 8 + 4);
            uint4 pk;
            pk.x = pack2(v0.x, v0.y); pk.y = pack2(v0.z, v0.w);
            pk.z = pack2(v1.x, v1.y); pk.w = pack2(v1.z, v1.w);
            *(uint4*)((char*)A + ((base + u * 16) ^ sw)) = pk;
        }
    }
    __syncthreads();

    const int lane = t & 63;
    const int w    = t >> 6;
    const int l15  = lane & 15;
    const int lhi  = lane >> 4;

    f32x4 acc[4][4];
    #pragma unroll
    for (int rf = 0; rf < 4; ++rf)
        #pragma unroll
        for (int nf = 0; nf < 4; ++nf)
            acc[rf][nf] = (f32x4){0.f, 0.f, 0.f, 0.f};

    const ushort* Wp = W_t + (size_t)(w * 64 + l15) * 256 + lhi * 8;
    const uint asw = (uint)((l15 & 7) << 4);

    for (int kk = 0; kk < 8; ++kk) {
        bf16x8 f[4];
        #pragma unroll
        for (int rf = 0; rf < 4; ++rf) {
            const uint ad = (uint)((rf * 16 + l15) * 512 + lhi * 16 + kk * 64);
            f[rf] = *(const bf16x8*)((const char*)A + (ad ^ asw));
        }
        #pragma unroll
        for (int nf = 0; nf < 4; ++nf) {
            bf16x8 wv = *(const bf16x8*)(Wp + (size_t)nf * 16 * 256 + kk * 32);
            #pragma unroll
            for (int rf = 0; rf < 4; ++rf)
                acc[rf][nf] = __builtin_amdgcn_mfma_f32_16x16x32_bf16(wv, f[rf], acc[rf][nf], 0, 0, 0);
        }
    }

    // bias add + per-wave row max (over this wave's 64 cols)
    float wmax[4];
    #pragma unroll
    for (int rf = 0; rf < 4; ++rf) {
        float lm = 0.f;
        #pragma unroll
        for (int nf = 0; nf < 4; ++nf) {
            const int n = w * 64 + nf * 16 + lhi * 4;
            float4 bb = *(const float4*)&b_in[n];
            acc[rf][nf][0] += bb.x; acc[rf][nf][1] += bb.y;
            acc[rf][nf][2] += bb.z; acc[rf][nf][3] += bb.w;
            lm = fmaxf(lm, fmaxf(fmaxf(fabsf(acc[rf][nf][0]), fabsf(acc[rf][nf][1])),
                                 fmaxf(fabsf(acc[rf][nf][2]), fabsf(acc[rf][nf][3]))));
        }
        wmax[rf] = pl32_max(pl16_max(lm));
    }
    if (lhi == 0) {
        #pragma unroll
        for (int rf = 0; rf < 4; ++rf)
            smax[w][rf * 16 + l15] = wmax[rf];
    }
    __syncthreads();

    #pragma unroll
    for (int rf = 0; rf < 4; ++rf) {
        const int row = rf * 16 + l15;
        const int m = m0 + row;
        float rm = fmaxf(fmaxf(smax[0][row], smax[1][row]),
                         fmaxf(smax[2][row], smax[3][row]));
        rm = fmaxf(rm, 1e-20f);
        const float qs = __fdividef(127.f, rm);
        if (m < N_NODES) {
            #pragma unroll
            for (int nf = 0; nf < 4; ++nf) {
                uint b0 = (uint)(int)rintf(fmaf(acc[rf][nf][0], qs, 128.f));
                uint b1 = (uint)(int)rintf(fmaf(acc[rf][nf][1], qs, 128.f));
                uint b2 = (uint)(int)rintf(fmaf(acc[rf][nf][2], qs, 128.f));
                uint b3 = (uint)(int)rintf(fmaf(acc[rf][nf][3], qs, 128.f));
                *(uint*)&q1[(size_t)m * 256 + w * 64 + nf * 16 + lhi * 4] =
                    b0 | (b1 << 8) | (b2 << 16) | (b3 << 24);
            }
            if (w == 0 && lhi == 0) rscale1[m] = rm * (1.f / 127.f);
        }
    }
}

// ---------------------------------------------------------------------------
// K2: hat1: z = mean_17(q1 rows, biased u8); l2 = log0(relu(exp0(z))),
// quantized to unsigned u8 q2 (vals >= 0) + rscale2.
// Wave/node: 4 groups x 16 lanes; group g rows {4j+g}, g0 adds self.
// ---------------------------------------------------------------------------
__global__ __launch_bounds__(256) void k_hat1_q(
    const uchar* __restrict__ q1, const float* __restrict__ rscale1,
    const int* __restrict__ src,
    uchar* __restrict__ q2, float* __restrict__ rscale2)
{
    const int lane = threadIdx.x & 63;
    const int g    = lane >> 4;
    const int pos  = lane & 15;
    const int v    = blockIdx.x * 4 + (threadIdx.x >> 6);
    const int vv   = __builtin_amdgcn_readfirstlane(v);
    const int* sp  = src + (size_t)vv * DEG;

    float acc[16];
    #pragma unroll
    for (int i = 0; i < 16; i++) acc[i] = 0.f;
    float srs = 0.f;

    #pragma unroll
    for (int j = 0; j < 4; j++) {
        const int s = sp[j * 4 + g];
        uint4 r = *(const uint4*)(q1 + ((size_t)s << 8) + pos * 16);
        float rs = rscale1[s];
        srs += rs;
        acc4(acc + 0, r.x, rs); acc4(acc + 4, r.y, rs);
        acc4(acc + 8, r.z, rs); acc4(acc + 12, r.w, rs);
    }
    if (g == 0) {
        uint4 r = *(const uint4*)(q1 + ((size_t)vv << 8) + pos * 16);
        float rs = rscale1[vv];
        srs += rs;
        acc4(acc + 0, r.x, rs); acc4(acc + 4, r.y, rs);
        acc4(acc + 8, r.z, rs); acc4(acc + 12, r.w, rs);
    }
    #pragma unroll
    for (int i = 0; i < 16; i++) {
        acc[i] = pl16_sum(acc[i]);
        acc[i] = pl32_sum(acc[i]);
    }
    srs = pl16_sum(srs);
    srs = pl32_sum(srs);

    const float inv = 1.f / (float)(DEG + 1);
    const float bias = 128.f * srs;
    float rz[16], ss = 0.f, ssp = 0.f;
    #pragma unroll
    for (int i = 0; i < 16; i++) {
        float z = (acc[i] - bias) * inv;
        ss += z * z;
        rz[i] = fmaxf(z, 0.f);
        ssp += rz[i] * rz[i];
    }
    ss  = red16_sum(ss);
    ssp = red16_sum(ssp);

    float se = tanh_over_x(fmaxf(sqrtf(ss), EPSF));
    float nh = se * sqrtf(ssp);
    float nc = fminf(fmaxf(nh, EPSF), 1.f - EPSF);
    float c  = atanh_over_x(nc) * se;

    float lmax = 0.f;
    #pragma unroll
    for (int i = 0; i < 16; i++) {
        rz[i] *= c;                       // final l2 values, >= 0
        lmax = fmaxf(lmax, rz[i]);
    }
    lmax = red16_max(lmax);
    lmax = fmaxf(lmax, 1e-20f);
    const float qs = __fdividef(255.f, lmax);

    if (g == 0) {
        uint d[4];
        #pragma unroll
        for (int k = 0; k < 4; k++) {
            uint b0 = (uint)(int)rintf(rz[4 * k + 0] * qs);
            uint b1 = (uint)(int)rintf(rz[4 * k + 1] * qs);
            uint b2 = (uint)(int)rintf(rz[4 * k + 2] * qs);
            uint b3 = (uint)(int)rintf(rz[4 * k + 3] * qs);
            d[k] = b0 | (b1 << 8) | (b2 << 16) | (b3 << 24);
        }
        uint4 o; o.x = d[0]; o.y = d[1]; o.z = d[2]; o.w = d[3];
        *(uint4*)(q2 + ((size_t)vv << 8) + pos * 16) = o;
        if (lane == 0) rscale2[vv] = lmax * (1.f / 255.f);
    }
}

// ---------------------------------------------------------------------------
// K3: hat2: z2 = mean_17(q2 rows, unsigned u8) -> bf16 z2b (identity map)
// ---------------------------------------------------------------------------
__global__ __launch_bounds__(256) void k_hat2_q(
    const uchar* __restrict__ q2, const float* __restrict__ rscale2,
    const int* __restrict__ src, ushort* __restrict__ z2b)
{
    const int lane = threadIdx.x & 63;
    const int g    = lane >> 4;
    const int pos  = lane & 15;
    const int v    = blockIdx.x * 4 + (threadIdx.x >> 6);
    const int vv   = __builtin_amdgcn_readfirstlane(v);
    const int* sp  = src + (size_t)vv * DEG;

    float acc[16];
    #pragma unroll
    for (int i = 0; i < 16; i++) acc[i] = 0.f;

    #pragma unroll
    for (int j = 0; j < 4; j++) {
        const int s = sp[j * 4 + g];
        uint4 r = *(const uint4*)(q2 + ((size_t)s << 8) + pos * 16);
        float rs = rscale2[s];
        acc4(acc + 0, r.x, rs); acc4(acc + 4, r.y, rs);
        acc4(acc + 8, r.z, rs); acc4(acc + 12, r.w, rs);
    }
    if (g == 0) {
        uint4 r = *(const uint4*)(q2 + ((size_t)vv << 8) + pos * 16);
        float rs = rscale2[vv];
        acc4(acc + 0, r.x, rs); acc4(acc + 4, r.y, rs);
        acc4(acc + 8, r.z, rs); acc4(acc + 12, r.w, rs);
    }
    #pragma unroll
    for (int i = 0; i < 16; i++) {
        acc[i] = pl16_sum(acc[i]);
        acc[i] = pl32_sum(acc[i]);
    }

    const float inv = 1.f / (float)(DEG + 1);
    if (g == 0) {
        uint4 o1, o2;
        o1.x = pack2(acc[0] * inv,  acc[1] * inv);
        o1.y = pack2(acc[2] * inv,  acc[3] * inv);
        o1.z = pack2(acc[4] * inv,  acc[5] * inv);
        o1.w = pack2(acc[6] * inv,  acc[7] * inv);
        o2.x = pack2(acc[8] * inv,  acc[9] * inv);
        o2.y = pack2(acc[10] * inv, acc[11] * inv);
        o2.z = pack2(acc[12] * inv, acc[13] * inv);
        o2.w = pack2(acc[14] * inv, acc[15] * inv);
        ushort* row = z2b + (size_t)vv * 256 + pos * 16;
        *(uint4*)row = o1;
        *(uint4*)(row + 8) = o2;
    }
}

// ---------------------------------------------------------------------------
// K4: out = exp0(z2 @ W_out + b_out)  (bf16 MFMA, swapped operands).
// ---------------------------------------------------------------------------
__global__ __launch_bounds__(256) void k_fc_out_mfma(
    const ushort* __restrict__ z2b, const ushort* __restrict__ Wo_t,
    const float* __restrict__ b_out, float* __restrict__ out)
{
    const int t    = threadIdx.x;
    const int lane = t & 63;
    const int w    = t >> 6;
    const int l15  = lane & 15;
    const int lhi  = lane >> 4;
    const int m0   = blockIdx.x * 128;

    f32x4 acc[2][8];
    #pragma unroll
    for (int rf = 0; rf < 2; ++rf)
        #pragma unroll
        for (int nf = 0; nf < 8; ++nf)
            acc[rf][nf] = (f32x4){0.f, 0.f, 0.f, 0.f};

    const ushort* Ap = z2b + (size_t)(m0 + w * 32 + l15) * 256 + lhi * 8;
    const ushort* Wp = Wo_t + (size_t)l15 * 256 + lhi * 8;

    for (int kk = 0; kk < 8; ++kk) {
        bf16x8 f0 = *(const bf16x8*)(Ap + kk * 32);
        bf16x8 f1 = *(const bf16x8*)(Ap + 16 * 256 + kk * 32);
        #pragma unroll
        for (int nf = 0; nf < 8; ++nf) {
            bf16x8 wv = *(const bf16x8*)(Wp + (size_t)nf * 16 * 256 + kk * 32);
            acc[0][nf] = __builtin_amdgcn_mfma_f32_16x16x32_bf16(wv, f0, acc[0][nf], 0, 0, 0);
            acc[1][nf] = __builtin_amdgcn_mfma_f32_16x16x32_bf16(wv, f1, acc[1][nf], 0, 0, 0);
        }
    }

    float4 bb[8];
    #pragma unroll
    for (int nf = 0; nf < 8; ++nf)
        bb[nf] = *(const float4*)&b_out[nf * 16 + lhi * 4];

    #pragma unroll
    for (int rf = 0; rf < 2; ++rf) {
        const int m = m0 + w * 32 + rf * 16 + l15;
        float ss = 0.f;
        #pragma unroll
        for (int nf = 0; nf < 8; ++nf) {
            float t0 = acc[rf][nf][0] + bb[nf].x;
            float t1 = acc[rf][nf][1] + bb[nf].y;
            float t2 = acc[rf][nf][2] + bb[nf].z;
            float t3 = acc[rf][nf][3] + bb[nf].w;
            acc[rf][nf][0] = t0; acc[rf][nf][1] = t1;
            acc[rf][nf][2] = t2; acc[rf][nf][3] = t3;
            ss += t0 * t0 + t1 * t1 + t2 * t2 + t3 * t3;
        }
        ss = pl16_sum(ss);
        ss = pl32_sum(ss);
        float norm = sqrtf(ss);
        float nm = fmaxf(norm, EPSF);
        float se = tanh_over_x(nm);
        if (m < N_NODES) {
            #pragma unroll
            for (int nf = 0; nf < 8; ++nf) {
                float4 o;
                o.x = se * acc[rf][nf][0];
                o.y = se * acc[rf][nf][1];
                o.z = se * acc[rf][nf][2];
                o.w = se * acc[rf][nf][3];
                *(float4*)&out[(size_t)m * 128 + nf * 16 + lhi * 4] = o;
            }
        }
    }
}

extern "C" void kernel_launch(void* const* d_in, const int* in_sizes, int n_in,
                              void* d_out, int out_size, void* d_ws, size_t ws_size,
                              hipStream_t stream) {
    const int*   x     = (const int*)  d_in[0];
    const float* emb0  = (const float*)d_in[1];
    const float* emb1  = (const float*)d_in[2];
    const float* emb2  = (const float*)d_in[3];
    const float* W_in  = (const float*)d_in[4];
    const float* b_in  = (const float*)d_in[5];
    const float* W_out = (const float*)d_in[6];
    const float* b_out = (const float*)d_in[7];
    const int*   src0  = (const int*)  d_in[8];
    const int*   src1  = (const int*)  d_in[10];
    float* out = (float*)d_out;

    const size_t QT = (size_t)N_NODES * 256;          // bytes per int8 table
    uchar* q1 = (uchar*)d_ws;                         // 12.8 MB
    uchar* q2 = q1 + QT;                              // 12.8 MB
    float* rscale1 = (float*)(q2 + QT);               // 200 KB
    float* rscale2 = rscale1 + N_NODES;               // 200 KB
    ushort* z2b  = (ushort*)(rscale2 + N_NODES);      // 25.6 MB
    ushort* W_t  = z2b + (size_t)N_NODES * 256;       // 128 KB
    ushort* Wo_t = W_t + 256 * 256;                   // 64 KB

    k_prep<<<384, 256, 0, stream>>>(W_in, W_out, W_t, Wo_t);
    k_encode_mfma<<<(N_NODES + 63) / 64, 256, 0, stream>>>(x, emb0, emb1, emb2, W_t, b_in, q1, rscale1);
    k_hat1_q<<<N_NODES / 4, 256, 0, stream>>>(q1, rscale1, src0, q2, rscale2);
    k_hat2_q<<<N_NODES / 4, 256, 0, stream>>>(q2, rscale2, src1, z2b);
    k_fc_out_mfma<<<(N_NODES + 127) / 128, 256, 0, stream>>>(z2b, Wo_t, b_out, out);
}

// Round 8
// 133.515 us; speedup vs baseline: 1.4145x; 1.1232x over previous
//
#include <hip/hip_runtime.h>
#include <math.h>

#define N_NODES 50000
#define DEG 16
#define EPSF 1e-5f

typedef unsigned int uint;
typedef unsigned short ushort;
typedef unsigned char uchar;

using bf16x8 = __attribute__((ext_vector_type(8))) short;
using f32x4  = __attribute__((ext_vector_type(4))) float;

__device__ __forceinline__ uint f2bf_rn(float f) {
    uint u = __float_as_uint(f);
    return (u + 0x7FFFu + ((u >> 16) & 1u)) >> 16;
}
__device__ __forceinline__ uint pack2(float a, float b) {
    return f2bf_rn(a) | (f2bf_rn(b) << 16);
}

// ---- VALU-only wave reductions --------------------------------------------
__device__ __forceinline__ float pl32_sum(float v) {
#if __has_builtin(__builtin_amdgcn_permlane32_swap)
    auto r = __builtin_amdgcn_permlane32_swap((int)__float_as_uint(v), (int)__float_as_uint(v), false, false);
    return __uint_as_float((uint)r[0]) + __uint_as_float((uint)r[1]);
#else
    return v + __shfl_xor(v, 32, 64);
#endif
}
__device__ __forceinline__ float pl16_sum(float v) {
#if __has_builtin(__builtin_amdgcn_permlane16_swap)
    auto r = __builtin_amdgcn_permlane16_swap((int)__float_as_uint(v), (int)__float_as_uint(v), false, false);
    return __uint_as_float((uint)r[0]) + __uint_as_float((uint)r[1]);
#else
    return v + __shfl_xor(v, 16, 64);
#endif
}
__device__ __forceinline__ float pl32_max(float v) {
#if __has_builtin(__builtin_amdgcn_permlane32_swap)
    auto r = __builtin_amdgcn_permlane32_swap((int)__float_as_uint(v), (int)__float_as_uint(v), false, false);
    return fmaxf(__uint_as_float((uint)r[0]), __uint_as_float((uint)r[1]));
#else
    return fmaxf(v, __shfl_xor(v, 32, 64));
#endif
}
__device__ __forceinline__ float pl16_max(float v) {
#if __has_builtin(__builtin_amdgcn_permlane16_swap)
    auto r = __builtin_amdgcn_permlane16_swap((int)__float_as_uint(v), (int)__float_as_uint(v), false, false);
    return fmaxf(__uint_as_float((uint)r[0]), __uint_as_float((uint)r[1]));
#else
    return fmaxf(v, __shfl_xor(v, 16, 64));
#endif
}
#define DPP_ROR_ADD(v, CTRL) \
    v += __uint_as_float((uint)__builtin_amdgcn_update_dpp(0, (int)__float_as_uint(v), (CTRL), 0xF, 0xF, false))

// full sum within each 16-lane DPP row
__device__ __forceinline__ float red16_sum(float v) {
    DPP_ROR_ADD(v, 0x121); DPP_ROR_ADD(v, 0x122);
    DPP_ROR_ADD(v, 0x124); DPP_ROR_ADD(v, 0x128);
    return v;
}

// ---- fast hyperbolic helpers ----------------------------------------------
__device__ __forceinline__ float tanh_over_x(float nm) {      // tanh(nm)/nm, nm>0
    float e = __expf(2.f * nm);
    float t = 1.f - __fdividef(2.f, e + 1.f);
    return __fdividef(t, nm);
}
__device__ __forceinline__ float atanh_over_x(float n) {      // atanh(n)/n, 0<n<1
    float l = __logf(__fdividef(1.f + n, 1.f - n));
    return 0.5f * __fdividef(l, n);
}

// ---- int8 decode: 4 ubytes of dw, acc[i] += ubyte_i * rs ------------------
__device__ __forceinline__ void acc4(float* acc, uint dw, float rs) {
    acc[0] = fmaf((float)(dw & 0xffu),         rs, acc[0]);
    acc[1] = fmaf((float)((dw >> 8) & 0xffu),  rs, acc[1]);
    acc[2] = fmaf((float)((dw >> 16) & 0xffu), rs, acc[2]);
    acc[3] = fmaf((float)(dw >> 24),           rs, acc[3]);
}

// ---------------------------------------------------------------------------
// K0: weight prep: W_t[n][k] = bf16(W_in[k][n]), Wo_t[n][k] = bf16(W_out[k][n])
// ---------------------------------------------------------------------------
__global__ __launch_bounds__(256) void k_prep(
    const float* __restrict__ W_in, const float* __restrict__ W_out,
    ushort* __restrict__ W_t, ushort* __restrict__ Wo_t)
{
    const int b = blockIdx.x, t = threadIdx.x;
    if (b < 256) {
        W_t[b * 256 + t] = (ushort)f2bf_rn(W_in[t * 256 + b]);
    } else {
        const int n = b - 256;
        Wo_t[n * 256 + t] = (ushort)f2bf_rn(W_out[t * 128 + n]);
    }
}

// ---------------------------------------------------------------------------
// K1: t = feat @ W_in + b_in (bf16 MFMA, swapped operands); quantize rows to
// biased-u8 q1 + rscale1 = rowmax/127.
// ---------------------------------------------------------------------------
__global__ __launch_bounds__(256) void k_encode_mfma(
    const int* __restrict__ x,
    const float* __restrict__ emb0, const float* __restrict__ emb1,
    const float* __restrict__ emb2,
    const ushort* __restrict__ W_t, const float* __restrict__ b_in,
    uchar* __restrict__ q1, float* __restrict__ rscale1)
{
    __shared__ ushort A[64 * 256];                  // 32 KB, swizzled
    __shared__ float smax[4][64];
    const int t  = threadIdx.x;
    const int m0 = blockIdx.x * 64;

    #pragma unroll
    for (int it = 0; it < 2; ++it) {
        const int nl   = it * 32 + (t >> 3);
        const int seg  = t & 7;
        const int node = m0 + nl;
        const int k0   = seg * 32;
        const float* p;
        if (node < N_NODES) {
            if (seg < 3)      p = emb0 + (size_t)x[node * 3 + 0] * 96 + k0;
            else if (seg < 6) p = emb1 + (size_t)x[node * 3 + 1] * 96 + (k0 - 96);
            else              p = emb2 + (size_t)x[node * 3 + 2] * 64 + (k0 - 192);
        } else {
            p = emb0;
        }
        const uint base = (uint)(nl * 512 + seg * 64);
        const uint sw   = (uint)((nl & 7) << 4);
        #pragma unroll
        for (int u = 0; u < 4; ++u) {
            float4 v0 = *(const float4*)(p + u * 8);
            float4 v1 = *(const float4*)(p + u * 8 + 4);
            uint4 pk;
            pk.x = pack2(v0.x, v0.y); pk.y = pack2(v0.z, v0.w);
            pk.z = pack2(v1.x, v1.y); pk.w = pack2(v1.z, v1.w);
            *(uint4*)((char*)A + ((base + u * 16) ^ sw)) = pk;
        }
    }
    __syncthreads();

    const int lane = t & 63;
    const int w    = t >> 6;
    const int l15  = lane & 15;
    const int lhi  = lane >> 4;

    f32x4 acc[4][4];
    #pragma unroll
    for (int rf = 0; rf < 4; ++rf)
        #pragma unroll
        for (int nf = 0; nf < 4; ++nf)
            acc[rf][nf] = (f32x4){0.f, 0.f, 0.f, 0.f};

    const ushort* Wp = W_t + (size_t)(w * 64 + l15) * 256 + lhi * 8;
    const uint asw = (uint)((l15 & 7) << 4);

    for (int kk = 0; kk < 8; ++kk) {
        bf16x8 f[4];
        #pragma unroll
        for (int rf = 0; rf < 4; ++rf) {
            const uint ad = (uint)((rf * 16 + l15) * 512 + lhi * 16 + kk * 64);
            f[rf] = *(const bf16x8*)((const char*)A + (ad ^ asw));
        }
        #pragma unroll
        for (int nf = 0; nf < 4; ++nf) {
            bf16x8 wv = *(const bf16x8*)(Wp + (size_t)nf * 16 * 256 + kk * 32);
            #pragma unroll
            for (int rf = 0; rf < 4; ++rf)
                acc[rf][nf] = __builtin_amdgcn_mfma_f32_16x16x32_bf16(wv, f[rf], acc[rf][nf], 0, 0, 0);
        }
    }

    float wmax[4];
    #pragma unroll
    for (int rf = 0; rf < 4; ++rf) {
        float lm = 0.f;
        #pragma unroll
        for (int nf = 0; nf < 4; ++nf) {
            const int n = w * 64 + nf * 16 + lhi * 4;
            float4 bb = *(const float4*)&b_in[n];
            acc[rf][nf][0] += bb.x; acc[rf][nf][1] += bb.y;
            acc[rf][nf][2] += bb.z; acc[rf][nf][3] += bb.w;
            lm = fmaxf(lm, fmaxf(fmaxf(fabsf(acc[rf][nf][0]), fabsf(acc[rf][nf][1])),
                                 fmaxf(fabsf(acc[rf][nf][2]), fabsf(acc[rf][nf][3]))));
        }
        wmax[rf] = pl32_max(pl16_max(lm));
    }
    if (lhi == 0) {
        #pragma unroll
        for (int rf = 0; rf < 4; ++rf)
            smax[w][rf * 16 + l15] = wmax[rf];
    }
    __syncthreads();

    #pragma unroll
    for (int rf = 0; rf < 4; ++rf) {
        const int row = rf * 16 + l15;
        const int m = m0 + row;
        float rm = fmaxf(fmaxf(smax[0][row], smax[1][row]),
                         fmaxf(smax[2][row], smax[3][row]));
        rm = fmaxf(rm, 1e-20f);
        const float qs = __fdividef(127.f, rm);
        if (m < N_NODES) {
            #pragma unroll
            for (int nf = 0; nf < 4; ++nf) {
                uint b0 = (uint)(int)rintf(fmaf(acc[rf][nf][0], qs, 128.f));
                uint b1 = (uint)(int)rintf(fmaf(acc[rf][nf][1], qs, 128.f));
                uint b2 = (uint)(int)rintf(fmaf(acc[rf][nf][2], qs, 128.f));
                uint b3 = (uint)(int)rintf(fmaf(acc[rf][nf][3], qs, 128.f));
                *(uint*)&q1[(size_t)m * 256 + w * 64 + nf * 16 + lhi * 4] =
                    b0 | (b1 << 8) | (b2 << 16) | (b3 << 24);
            }
            if (w == 0 && lhi == 0) rscale1[m] = rm * (1.f / 127.f);
        }
    }
}

// ---------------------------------------------------------------------------
// K2: hat1: z = mean_17(q1 rows); l2 = log0(relu(exp0(z))) -> bf16 (dense out)
// Wave/node: 4 groups x 16 lanes; group g rows {4j+g}, g3 adds self.
// ---------------------------------------------------------------------------
__global__ __launch_bounds__(256) void k_hat1_q(
    const uchar* __restrict__ q1, const float* __restrict__ rscale1,
    const int* __restrict__ src, ushort* __restrict__ l2)
{
    const int lane = threadIdx.x & 63;
    const int g    = lane >> 4;
    const int pos  = lane & 15;
    const int v    = blockIdx.x * 4 + (threadIdx.x >> 6);
    const int vv   = __builtin_amdgcn_readfirstlane(v);
    const int* sp  = src + (size_t)vv * DEG;

    float acc[16];
    #pragma unroll
    for (int i = 0; i < 16; i++) acc[i] = 0.f;
    float srs = 0.f;

    #pragma unroll
    for (int j = 0; j < 4; j++) {
        const int s = sp[j * 4 + g];
        uint4 r = *(const uint4*)(q1 + ((size_t)s << 8) + pos * 16);
        float rs = rscale1[s];
        srs += rs;
        acc4(acc + 0, r.x, rs); acc4(acc + 4, r.y, rs);
        acc4(acc + 8, r.z, rs); acc4(acc + 12, r.w, rs);
    }
    if (g == 3) {
        uint4 r = *(const uint4*)(q1 + ((size_t)vv << 8) + pos * 16);
        float rs = rscale1[vv];
        srs += rs;
        acc4(acc + 0, r.x, rs); acc4(acc + 4, r.y, rs);
        acc4(acc + 8, r.z, rs); acc4(acc + 12, r.w, rs);
    }
    #pragma unroll
    for (int i = 0; i < 16; i++) {
        acc[i] = pl16_sum(acc[i]);
        acc[i] = pl32_sum(acc[i]);
    }
    srs = pl16_sum(srs);
    srs = pl32_sum(srs);

    const float inv = 1.f / (float)(DEG + 1);
    const float bias = 128.f * srs;
    float rz[16], ss = 0.f, ssp = 0.f;
    #pragma unroll
    for (int i = 0; i < 16; i++) {
        float z = (acc[i] - bias) * inv;
        ss += z * z;
        rz[i] = fmaxf(z, 0.f);
        ssp += rz[i] * rz[i];
    }
    ss  = red16_sum(ss);
    ssp = red16_sum(ssp);

    float se = tanh_over_x(fmaxf(sqrtf(ss), EPSF));
    float nh = se * sqrtf(ssp);
    float nc = fminf(fmaxf(nh, EPSF), 1.f - EPSF);
    float c  = atanh_over_x(nc) * se;

    if (g == 0) {
        uint4 o1, o2;
        o1.x = pack2(c * rz[0],  c * rz[1]);
        o1.y = pack2(c * rz[2],  c * rz[3]);
        o1.z = pack2(c * rz[4],  c * rz[5]);
        o1.w = pack2(c * rz[6],  c * rz[7]);
        o2.x = pack2(c * rz[8],  c * rz[9]);
        o2.y = pack2(c * rz[10], c * rz[11]);
        o2.z = pack2(c * rz[12], c * rz[13]);
        o2.w = pack2(c * rz[14], c * rz[15]);
        ushort* row = l2 + (size_t)vv * 256 + pos * 16;
        *(uint4*)row = o1;
        *(uint4*)(row + 8) = o2;
    }
}

// ---------------------------------------------------------------------------
// K3: y = l2 @ W_out + b_out (bf16 MFMA, swapped operands), quantized per-row
// to biased-u8 qy (128 B rows) + rscale_y.  (fc pushed ahead of hat2 by
// linearity: mean(rows)@W + b == mean(rows@W + b))
// ---------------------------------------------------------------------------
__global__ __launch_bounds__(256) void k_fc_y(
    const ushort* __restrict__ l2, const ushort* __restrict__ Wo_t,
    const float* __restrict__ b_out,
    uchar* __restrict__ qy, float* __restrict__ rscale_y)
{
    const int t    = threadIdx.x;
    const int lane = t & 63;
    const int w    = t >> 6;
    const int l15  = lane & 15;
    const int lhi  = lane >> 4;
    const int m0   = blockIdx.x * 128;

    f32x4 acc[2][8];
    #pragma unroll
    for (int rf = 0; rf < 2; ++rf)
        #pragma unroll
        for (int nf = 0; nf < 8; ++nf)
            acc[rf][nf] = (f32x4){0.f, 0.f, 0.f, 0.f};

    const int ar0 = min(m0 + w * 32 + l15,      N_NODES - 1);
    const int ar1 = min(m0 + w * 32 + 16 + l15, N_NODES - 1);
    const ushort* Ap0 = l2 + (size_t)ar0 * 256 + lhi * 8;
    const ushort* Ap1 = l2 + (size_t)ar1 * 256 + lhi * 8;
    const ushort* Wp  = Wo_t + (size_t)l15 * 256 + lhi * 8;

    for (int kk = 0; kk < 8; ++kk) {
        bf16x8 f0 = *(const bf16x8*)(Ap0 + kk * 32);
        bf16x8 f1 = *(const bf16x8*)(Ap1 + kk * 32);
        #pragma unroll
        for (int nf = 0; nf < 8; ++nf) {
            bf16x8 wv = *(const bf16x8*)(Wp + (size_t)nf * 16 * 256 + kk * 32);
            acc[0][nf] = __builtin_amdgcn_mfma_f32_16x16x32_bf16(wv, f0, acc[0][nf], 0, 0, 0);
            acc[1][nf] = __builtin_amdgcn_mfma_f32_16x16x32_bf16(wv, f1, acc[1][nf], 0, 0, 0);
        }
    }

    float4 bb[8];
    #pragma unroll
    for (int nf = 0; nf < 8; ++nf)
        bb[nf] = *(const float4*)&b_out[nf * 16 + lhi * 4];

    #pragma unroll
    for (int rf = 0; rf < 2; ++rf) {
        const int m = m0 + w * 32 + rf * 16 + l15;
        float lm = 0.f;
        #pragma unroll
        for (int nf = 0; nf < 8; ++nf) {
            float t0 = acc[rf][nf][0] + bb[nf].x;
            float t1 = acc[rf][nf][1] + bb[nf].y;
            float t2 = acc[rf][nf][2] + bb[nf].z;
            float t3 = acc[rf][nf][3] + bb[nf].w;
            acc[rf][nf][0] = t0; acc[rf][nf][1] = t1;
            acc[rf][nf][2] = t2; acc[rf][nf][3] = t3;
            lm = fmaxf(lm, fmaxf(fmaxf(fabsf(t0), fabsf(t1)),
                                 fmaxf(fabsf(t2), fabsf(t3))));
        }
        // row max across the 4 lanes sharing l15 (lhi = 0..3)
        lm = pl16_max(lm);
        lm = pl32_max(lm);
        lm = fmaxf(lm, 1e-20f);
        const float qs = __fdividef(127.f, lm);
        if (m < N_NODES) {
            #pragma unroll
            for (int nf = 0; nf < 8; ++nf) {
                uint b0 = (uint)(int)rintf(fmaf(acc[rf][nf][0], qs, 128.f));
                uint b1 = (uint)(int)rintf(fmaf(acc[rf][nf][1], qs, 128.f));
                uint b2 = (uint)(int)rintf(fmaf(acc[rf][nf][2], qs, 128.f));
                uint b3 = (uint)(int)rintf(fmaf(acc[rf][nf][3], qs, 128.f));
                *(uint*)&qy[(size_t)m * 128 + nf * 16 + lhi * 4] =
                    b0 | (b1 << 8) | (b2 << 16) | (b3 << 24);
            }
            if (lhi == 0) rscale_y[m] = lm * (1.f / 127.f);
        }
    }
}

// ---------------------------------------------------------------------------
// K4: out = exp0(mean_17(qy rows))   (128 B rows, biased u8)
// Wave/node: 4 groups x 16 lanes, 8 B/lane chunk; group g rows {4j+g}, g3+self.
// ---------------------------------------------------------------------------
__global__ __launch_bounds__(256) void k_hat2_q(
    const uchar* __restrict__ qy, const float* __restrict__ rscale_y,
    const int* __restrict__ src, float* __restrict__ out)
{
    const int lane = threadIdx.x & 63;
    const int g    = lane >> 4;
    const int pos  = lane & 15;         // 8 B chunk within 128 B row
    const int v    = blockIdx.x * 4 + (threadIdx.x >> 6);
    const int vv   = __builtin_amdgcn_readfirstlane(v);
    const int* sp  = src + (size_t)vv * DEG;

    float acc[8];
    #pragma unroll
    for (int i = 0; i < 8; i++) acc[i] = 0.f;
    float srs = 0.f;

    #pragma unroll
    for (int j = 0; j < 4; j++) {
        const int s = sp[j * 4 + g];
        uint2 r = *(const uint2*)(qy + ((size_t)s << 7) + pos * 8);
        float rs = rscale_y[s];
        srs += rs;
        acc4(acc + 0, r.x, rs); acc4(acc + 4, r.y, rs);
    }
    if (g == 3) {
        uint2 r = *(const uint2*)(qy + ((size_t)vv << 7) + pos * 8);
        float rs = rscale_y[vv];
        srs += rs;
        acc4(acc + 0, r.x, rs); acc4(acc + 4, r.y, rs);
    }
    #pragma unroll
    for (int i = 0; i < 8; i++) {
        acc[i] = pl16_sum(acc[i]);
        acc[i] = pl32_sum(acc[i]);
    }
    srs = pl16_sum(srs);
    srs = pl32_sum(srs);

    const float inv = 1.f / (float)(DEG + 1);
    const float bias = 128.f * srs;
    float z[8], ss = 0.f;
    #pragma unroll
    for (int i = 0; i < 8; i++) {
        z[i] = (acc[i] - bias) * inv;
        ss += z[i] * z[i];
    }
    ss = red16_sum(ss);                 // 16 pos-lanes, each pos once

    float se = tanh_over_x(fmaxf(sqrtf(ss), EPSF));

    if (g == 0) {
        float4 o0, o1;
        o0.x = se * z[0]; o0.y = se * z[1]; o0.z = se * z[2]; o0.w = se * z[3];
        o1.x = se * z[4]; o1.y = se * z[5]; o1.z = se * z[6]; o1.w = se * z[7];
        float* row = out + (size_t)vv * 128 + pos * 8;
        *(float4*)row = o0;
        *(float4*)(row + 4) = o1;
    }
}

extern "C" void kernel_launch(void* const* d_in, const int* in_sizes, int n_in,
                              void* d_out, int out_size, void* d_ws, size_t ws_size,
                              hipStream_t stream) {
    const int*   x     = (const int*)  d_in[0];
    const float* emb0  = (const float*)d_in[1];
    const float* emb1  = (const float*)d_in[2];
    const float* emb2  = (const float*)d_in[3];
    const float* W_in  = (const float*)d_in[4];
    const float* b_in  = (const float*)d_in[5];
    const float* W_out = (const float*)d_in[6];
    const float* b_out = (const float*)d_in[7];
    const int*   src0  = (const int*)  d_in[8];
    const int*   src1  = (const int*)  d_in[10];
    float* out = (float*)d_out;

    uchar*  q1       = (uchar*)d_ws;                        // 12.8 MB
    ushort* l2       = (ushort*)(q1 + (size_t)N_NODES * 256);   // 25.6 MB
    uchar*  qy       = (uchar*)(l2 + (size_t)N_NODES * 256);    // 6.4 MB
    float*  rscale1  = (float*)(qy + (size_t)N_NODES * 128);    // 200 KB
    float*  rscale_y = rscale1 + N_NODES;                       // 200 KB
    ushort* W_t      = (ushort*)(rscale_y + N_NODES);           // 128 KB
    ushort* Wo_t     = W_t + 256 * 256;                         // 64 KB

    k_prep<<<384, 256, 0, stream>>>(W_in, W_out, W_t, Wo_t);
    k_encode_mfma<<<(N_NODES + 63) / 64, 256, 0, stream>>>(x, emb0, emb1, emb2, W_t, b_in, q1, rscale1);
    k_hat1_q<<<N_NODES / 4, 256, 0, stream>>>(q1, rscale1, src0, l2);
    k_fc_y<<<(N_NODES + 127) / 128, 256, 0, stream>>>(l2, Wo_t, b_out, qy, rscale_y);
    k_hat2_q<<<N_NODES / 4, 256, 0, stream>>>(qy, rscale_y, src1, out);
}

// Round 9
// 116.419 us; speedup vs baseline: 1.6222x; 1.1468x over previous
//
#include <hip/hip_runtime.h>
#include <math.h>

#define N_NODES 50000
#define DEG 16
#define EPSF 1e-5f

typedef unsigned int uint;
typedef unsigned short ushort;
typedef unsigned char uchar;

using bf16x8 = __attribute__((ext_vector_type(8))) short;
using f32x4  = __attribute__((ext_vector_type(4))) float;

__device__ __forceinline__ uint f2bf_rn(float f) {
    uint u = __float_as_uint(f);
    return (u + 0x7FFFu + ((u >> 16) & 1u)) >> 16;
}
__device__ __forceinline__ uint pack2(float a, float b) {
    return f2bf_rn(a) | (f2bf_rn(b) << 16);
}

// ---- VALU-only wave reductions --------------------------------------------
__device__ __forceinline__ float pl32_sum(float v) {
#if __has_builtin(__builtin_amdgcn_permlane32_swap)
    auto r = __builtin_amdgcn_permlane32_swap((int)__float_as_uint(v), (int)__float_as_uint(v), false, false);
    return __uint_as_float((uint)r[0]) + __uint_as_float((uint)r[1]);
#else
    return v + __shfl_xor(v, 32, 64);
#endif
}
__device__ __forceinline__ float pl16_sum(float v) {
#if __has_builtin(__builtin_amdgcn_permlane16_swap)
    auto r = __builtin_amdgcn_permlane16_swap((int)__float_as_uint(v), (int)__float_as_uint(v), false, false);
    return __uint_as_float((uint)r[0]) + __uint_as_float((uint)r[1]);
#else
    return v + __shfl_xor(v, 16, 64);
#endif
}
__device__ __forceinline__ float pl32_max(float v) {
#if __has_builtin(__builtin_amdgcn_permlane32_swap)
    auto r = __builtin_amdgcn_permlane32_swap((int)__float_as_uint(v), (int)__float_as_uint(v), false, false);
    return fmaxf(__uint_as_float((uint)r[0]), __uint_as_float((uint)r[1]));
#else
    return fmaxf(v, __shfl_xor(v, 32, 64));
#endif
}
__device__ __forceinline__ float pl16_max(float v) {
#if __has_builtin(__builtin_amdgcn_permlane16_swap)
    auto r = __builtin_amdgcn_permlane16_swap((int)__float_as_uint(v), (int)__float_as_uint(v), false, false);
    return fmaxf(__uint_as_float((uint)r[0]), __uint_as_float((uint)r[1]));
#else
    return fmaxf(v, __shfl_xor(v, 16, 64));
#endif
}
#define DPP_ROR_ADD(v, CTRL) \
    v += __uint_as_float((uint)__builtin_amdgcn_update_dpp(0, (int)__float_as_uint(v), (CTRL), 0xF, 0xF, false))

// full sum within each 16-lane DPP row (all 16 lanes get the total)
__device__ __forceinline__ float red16_sum(float v) {
    DPP_ROR_ADD(v, 0x121); DPP_ROR_ADD(v, 0x122);
    DPP_ROR_ADD(v, 0x124); DPP_ROR_ADD(v, 0x128);
    return v;
}

// ---- fast hyperbolic helpers ----------------------------------------------
__device__ __forceinline__ float tanh_over_x(float nm) {      // tanh(nm)/nm, nm>0
    float e = __expf(2.f * nm);
    float t = 1.f - __fdividef(2.f, e + 1.f);
    return __fdividef(t, nm);
}
__device__ __forceinline__ float atanh_over_x(float n) {      // atanh(n)/n, 0<n<1
    float l = __logf(__fdividef(1.f + n, 1.f - n));
    return 0.5f * __fdividef(l, n);
}

// ---- int8 decode: 4 ubytes of dw, acc[i] += ubyte_i * rs ------------------
__device__ __forceinline__ void acc4(float* acc, uint dw, float rs) {
    acc[0] = fmaf((float)(dw & 0xffu),         rs, acc[0]);
    acc[1] = fmaf((float)((dw >> 8) & 0xffu),  rs, acc[1]);
    acc[2] = fmaf((float)((dw >> 16) & 0xffu), rs, acc[2]);
    acc[3] = fmaf((float)(dw >> 24),           rs, acc[3]);
}

// ---------------------------------------------------------------------------
// K0: weight prep: W_t[n][k] = bf16(W_in[k][n]), Wo_t[n][k] = bf16(W_out[k][n])
// ---------------------------------------------------------------------------
__global__ __launch_bounds__(256) void k_prep(
    const float* __restrict__ W_in, const float* __restrict__ W_out,
    ushort* __restrict__ W_t, ushort* __restrict__ Wo_t)
{
    const int b = blockIdx.x, t = threadIdx.x;
    if (b < 256) {
        W_t[b * 256 + t] = (ushort)f2bf_rn(W_in[t * 256 + b]);
    } else {
        const int n = b - 256;
        Wo_t[n * 256 + t] = (ushort)f2bf_rn(W_out[t * 128 + n]);
    }
}

// ---------------------------------------------------------------------------
// K1: t = feat @ W_in + b_in (bf16 MFMA, swapped operands); quantize rows to
// biased-u8 q1 + rscale1 = rowmax/127.
// ---------------------------------------------------------------------------
__global__ __launch_bounds__(256) void k_encode_mfma(
    const int* __restrict__ x,
    const float* __restrict__ emb0, const float* __restrict__ emb1,
    const float* __restrict__ emb2,
    const ushort* __restrict__ W_t, const float* __restrict__ b_in,
    uchar* __restrict__ q1, float* __restrict__ rscale1)
{
    __shared__ ushort A[64 * 256];                  // 32 KB, swizzled
    __shared__ float smax[4][64];
    const int t  = threadIdx.x;
    const int m0 = blockIdx.x * 64;

    #pragma unroll
    for (int it = 0; it < 2; ++it) {
        const int nl   = it * 32 + (t >> 3);
        const int seg  = t & 7;
        const int node = m0 + nl;
        const int k0   = seg * 32;
        const float* p;
        if (node < N_NODES) {
            if (seg < 3)      p = emb0 + (size_t)x[node * 3 + 0] * 96 + k0;
            else if (seg < 6) p = emb1 + (size_t)x[node * 3 + 1] * 96 + (k0 - 96);
            else              p = emb2 + (size_t)x[node * 3 + 2] * 64 + (k0 - 192);
        } else {
            p = emb0;
        }
        const uint base = (uint)(nl * 512 + seg * 64);
        const uint sw   = (uint)((nl & 7) << 4);
        #pragma unroll
        for (int u = 0; u < 4; ++u) {
            float4 v0 = *(const float4*)(p + u * 8);
            float4 v1 = *(const float4*)(p + u * 8 + 4);
            uint4 pk;
            pk.x = pack2(v0.x, v0.y); pk.y = pack2(v0.z, v0.w);
            pk.z = pack2(v1.x, v1.y); pk.w = pack2(v1.z, v1.w);
            *(uint4*)((char*)A + ((base + u * 16) ^ sw)) = pk;
        }
    }
    __syncthreads();

    const int lane = t & 63;
    const int w    = t >> 6;
    const int l15  = lane & 15;
    const int lhi  = lane >> 4;

    f32x4 acc[4][4];
    #pragma unroll
    for (int rf = 0; rf < 4; ++rf)
        #pragma unroll
        for (int nf = 0; nf < 4; ++nf)
            acc[rf][nf] = (f32x4){0.f, 0.f, 0.f, 0.f};

    const ushort* Wp = W_t + (size_t)(w * 64 + l15) * 256 + lhi * 8;
    const uint asw = (uint)((l15 & 7) << 4);

    for (int kk = 0; kk < 8; ++kk) {
        bf16x8 f[4];
        #pragma unroll
        for (int rf = 0; rf < 4; ++rf) {
            const uint ad = (uint)((rf * 16 + l15) * 512 + lhi * 16 + kk * 64);
            f[rf] = *(const bf16x8*)((const char*)A + (ad ^ asw));
        }
        #pragma unroll
        for (int nf = 0; nf < 4; ++nf) {
            bf16x8 wv = *(const bf16x8*)(Wp + (size_t)nf * 16 * 256 + kk * 32);
            #pragma unroll
            for (int rf = 0; rf < 4; ++rf)
                acc[rf][nf] = __builtin_amdgcn_mfma_f32_16x16x32_bf16(wv, f[rf], acc[rf][nf], 0, 0, 0);
        }
    }

    float wmax[4];
    #pragma unroll
    for (int rf = 0; rf < 4; ++rf) {
        float lm = 0.f;
        #pragma unroll
        for (int nf = 0; nf < 4; ++nf) {
            const int n = w * 64 + nf * 16 + lhi * 4;
            float4 bb = *(const float4*)&b_in[n];
            acc[rf][nf][0] += bb.x; acc[rf][nf][1] += bb.y;
            acc[rf][nf][2] += bb.z; acc[rf][nf][3] += bb.w;
            lm = fmaxf(lm, fmaxf(fmaxf(fabsf(acc[rf][nf][0]), fabsf(acc[rf][nf][1])),
                                 fmaxf(fabsf(acc[rf][nf][2]), fabsf(acc[rf][nf][3]))));
        }
        wmax[rf] = pl32_max(pl16_max(lm));
    }
    if (lhi == 0) {
        #pragma unroll
        for (int rf = 0; rf < 4; ++rf)
            smax[w][rf * 16 + l15] = wmax[rf];
    }
    __syncthreads();

    #pragma unroll
    for (int rf = 0; rf < 4; ++rf) {
        const int row = rf * 16 + l15;
        const int m = m0 + row;
        float rm = fmaxf(fmaxf(smax[0][row], smax[1][row]),
                         fmaxf(smax[2][row], smax[3][row]));
        rm = fmaxf(rm, 1e-20f);
        const float qs = __fdividef(127.f, rm);
        if (m < N_NODES) {
            #pragma unroll
            for (int nf = 0; nf < 4; ++nf) {
                uint b0 = (uint)(int)rintf(fmaf(acc[rf][nf][0], qs, 128.f));
                uint b1 = (uint)(int)rintf(fmaf(acc[rf][nf][1], qs, 128.f));
                uint b2 = (uint)(int)rintf(fmaf(acc[rf][nf][2], qs, 128.f));
                uint b3 = (uint)(int)rintf(fmaf(acc[rf][nf][3], qs, 128.f));
                *(uint*)&q1[(size_t)m * 256 + w * 64 + nf * 16 + lhi * 4] =
                    b0 | (b1 << 8) | (b2 << 16) | (b3 << 24);
            }
            if (w == 0 && lhi == 0) rscale1[m] = rm * (1.f / 127.f);
        }
    }
}

// ---------------------------------------------------------------------------
// K2: hat1: z = mean_17(q1 rows); l2 = log0(relu(exp0(z))) -> bf16 (dense out)
// 16-lane group per node, lane owns a 16 B column chunk -> lane-private accs.
// Block = 256 thr = 16 nodes. src indices staged in LDS (broadcast reads).
// ---------------------------------------------------------------------------
__global__ __launch_bounds__(256) void k_hat1_q(
    const uchar* __restrict__ q1, const float* __restrict__ rscale1,
    const int* __restrict__ src, ushort* __restrict__ l2)
{
    __shared__ int lsrc[256];
    const int tid = threadIdx.x;
    const int gi  = tid >> 4;           // group 0..15 = node within block
    const int p   = tid & 15;           // 16 B chunk within 256 B row
    const int vb  = blockIdx.x * 16;    // 50000 = 3125*16, exact
    const int v   = vb + gi;

    lsrc[tid] = src[(size_t)vb * DEG + tid];
    __syncthreads();

    float acc[16];
    #pragma unroll
    for (int i = 0; i < 16; i++) acc[i] = 0.f;
    float srs = 0.f;

    #pragma unroll 4
    for (int j = 0; j < DEG; ++j) {
        const int s = lsrc[(gi << 4) | j];
        uint4 r = *(const uint4*)(q1 + ((size_t)s << 8) + p * 16);
        float rs = rscale1[s];
        srs += rs;
        acc4(acc + 0, r.x, rs); acc4(acc + 4, r.y, rs);
        acc4(acc + 8, r.z, rs); acc4(acc + 12, r.w, rs);
    }
    {   // self row
        uint4 r = *(const uint4*)(q1 + ((size_t)v << 8) + p * 16);
        float rs = rscale1[v];
        srs += rs;
        acc4(acc + 0, r.x, rs); acc4(acc + 4, r.y, rs);
        acc4(acc + 8, r.z, rs); acc4(acc + 12, r.w, rs);
    }

    const float inv = 1.f / (float)(DEG + 1);
    const float bias = 128.f * srs;
    float rz[16], ss = 0.f, ssp = 0.f;
    #pragma unroll
    for (int i = 0; i < 16; i++) {
        float z = (acc[i] - bias) * inv;
        ss += z * z;
        rz[i] = fmaxf(z, 0.f);
        ssp += rz[i] * rz[i];
    }
    ss  = red16_sum(ss);
    ssp = red16_sum(ssp);

    float se = tanh_over_x(fmaxf(sqrtf(ss), EPSF));
    float nh = se * sqrtf(ssp);
    float nc = fminf(fmaxf(nh, EPSF), 1.f - EPSF);
    float c  = atanh_over_x(nc) * se;

    uint4 o1, o2;
    o1.x = pack2(c * rz[0],  c * rz[1]);
    o1.y = pack2(c * rz[2],  c * rz[3]);
    o1.z = pack2(c * rz[4],  c * rz[5]);
    o1.w = pack2(c * rz[6],  c * rz[7]);
    o2.x = pack2(c * rz[8],  c * rz[9]);
    o2.y = pack2(c * rz[10], c * rz[11]);
    o2.z = pack2(c * rz[12], c * rz[13]);
    o2.w = pack2(c * rz[14], c * rz[15]);
    ushort* row = l2 + (size_t)v * 256 + p * 16;
    *(uint4*)row = o1;
    *(uint4*)(row + 8) = o2;
}

// ---------------------------------------------------------------------------
// K3: y = l2 @ W_out + b_out (bf16 MFMA, swapped operands), quantized per-row
// to biased-u8 qy (128 B rows) + rscale_y.
// ---------------------------------------------------------------------------
__global__ __launch_bounds__(256) void k_fc_y(
    const ushort* __restrict__ l2, const ushort* __restrict__ Wo_t,
    const float* __restrict__ b_out,
    uchar* __restrict__ qy, float* __restrict__ rscale_y)
{
    const int t    = threadIdx.x;
    const int lane = t & 63;
    const int w    = t >> 6;
    const int l15  = lane & 15;
    const int lhi  = lane >> 4;
    const int m0   = blockIdx.x * 128;

    f32x4 acc[2][8];
    #pragma unroll
    for (int rf = 0; rf < 2; ++rf)
        #pragma unroll
        for (int nf = 0; nf < 8; ++nf)
            acc[rf][nf] = (f32x4){0.f, 0.f, 0.f, 0.f};

    const int ar0 = min(m0 + w * 32 + l15,      N_NODES - 1);
    const int ar1 = min(m0 + w * 32 + 16 + l15, N_NODES - 1);
    const ushort* Ap0 = l2 + (size_t)ar0 * 256 + lhi * 8;
    const ushort* Ap1 = l2 + (size_t)ar1 * 256 + lhi * 8;
    const ushort* Wp  = Wo_t + (size_t)l15 * 256 + lhi * 8;

    for (int kk = 0; kk < 8; ++kk) {
        bf16x8 f0 = *(const bf16x8*)(Ap0 + kk * 32);
        bf16x8 f1 = *(const bf16x8*)(Ap1 + kk * 32);
        #pragma unroll
        for (int nf = 0; nf < 8; ++nf) {
            bf16x8 wv = *(const bf16x8*)(Wp + (size_t)nf * 16 * 256 + kk * 32);
            acc[0][nf] = __builtin_amdgcn_mfma_f32_16x16x32_bf16(wv, f0, acc[0][nf], 0, 0, 0);
            acc[1][nf] = __builtin_amdgcn_mfma_f32_16x16x32_bf16(wv, f1, acc[1][nf], 0, 0, 0);
        }
    }

    float4 bb[8];
    #pragma unroll
    for (int nf = 0; nf < 8; ++nf)
        bb[nf] = *(const float4*)&b_out[nf * 16 + lhi * 4];

    #pragma unroll
    for (int rf = 0; rf < 2; ++rf) {
        const int m = m0 + w * 32 + rf * 16 + l15;
        float lm = 0.f;
        #pragma unroll
        for (int nf = 0; nf < 8; ++nf) {
            float t0 = acc[rf][nf][0] + bb[nf].x;
            float t1 = acc[rf][nf][1] + bb[nf].y;
            float t2 = acc[rf][nf][2] + bb[nf].z;
            float t3 = acc[rf][nf][3] + bb[nf].w;
            acc[rf][nf][0] = t0; acc[rf][nf][1] = t1;
            acc[rf][nf][2] = t2; acc[rf][nf][3] = t3;
            lm = fmaxf(lm, fmaxf(fmaxf(fabsf(t0), fabsf(t1)),
                                 fmaxf(fabsf(t2), fabsf(t3))));
        }
        lm = pl16_max(lm);
        lm = pl32_max(lm);
        lm = fmaxf(lm, 1e-20f);
        const float qs = __fdividef(127.f, lm);
        if (m < N_NODES) {
            #pragma unroll
            for (int nf = 0; nf < 8; ++nf) {
                uint b0 = (uint)(int)rintf(fmaf(acc[rf][nf][0], qs, 128.f));
                uint b1 = (uint)(int)rintf(fmaf(acc[rf][nf][1], qs, 128.f));
                uint b2 = (uint)(int)rintf(fmaf(acc[rf][nf][2], qs, 128.f));
                uint b3 = (uint)(int)rintf(fmaf(acc[rf][nf][3], qs, 128.f));
                *(uint*)&qy[(size_t)m * 128 + nf * 16 + lhi * 4] =
                    b0 | (b1 << 8) | (b2 << 16) | (b3 << 24);
            }
            if (lhi == 0) rscale_y[m] = lm * (1.f / 127.f);
        }
    }
}

// ---------------------------------------------------------------------------
// K4: out = exp0(mean_17(qy rows))   (128 B rows, biased u8)
// 16-lane group per node, lane owns an 8 B chunk -> lane-private accs.
// ---------------------------------------------------------------------------
__global__ __launch_bounds__(256) void k_hat2_q(
    const uchar* __restrict__ qy, const float* __restrict__ rscale_y,
    const int* __restrict__ src, float* __restrict__ out)
{
    __shared__ int lsrc[256];
    const int tid = threadIdx.x;
    const int gi  = tid >> 4;
    const int p   = tid & 15;           // 8 B chunk within 128 B row
    const int vb  = blockIdx.x * 16;
    const int v   = vb + gi;

    lsrc[tid] = src[(size_t)vb * DEG + tid];
    __syncthreads();

    float acc[8];
    #pragma unroll
    for (int i = 0; i < 8; i++) acc[i] = 0.f;
    float srs = 0.f;

    #pragma unroll 4
    for (int j = 0; j < DEG; ++j) {
        const int s = lsrc[(gi << 4) | j];
        uint2 r = *(const uint2*)(qy + ((size_t)s << 7) + p * 8);
        float rs = rscale_y[s];
        srs += rs;
        acc4(acc + 0, r.x, rs); acc4(acc + 4, r.y, rs);
    }
    {   // self row
        uint2 r = *(const uint2*)(qy + ((size_t)v << 7) + p * 8);
        float rs = rscale_y[v];
        srs += rs;
        acc4(acc + 0, r.x, rs); acc4(acc + 4, r.y, rs);
    }

    const float inv = 1.f / (float)(DEG + 1);
    const float bias = 128.f * srs;
    float z[8], ss = 0.f;
    #pragma unroll
    for (int i = 0; i < 8; i++) {
        z[i] = (acc[i] - bias) * inv;
        ss += z[i] * z[i];
    }
    ss = red16_sum(ss);

    float se = tanh_over_x(fmaxf(sqrtf(ss), EPSF));

    float4 o0, o1;
    o0.x = se * z[0]; o0.y = se * z[1]; o0.z = se * z[2]; o0.w = se * z[3];
    o1.x = se * z[4]; o1.y = se * z[5]; o1.z = se * z[6]; o1.w = se * z[7];
    float* row = out + (size_t)v * 128 + p * 8;
    *(float4*)row = o0;
    *(float4*)(row + 4) = o1;
}

extern "C" void kernel_launch(void* const* d_in, const int* in_sizes, int n_in,
                              void* d_out, int out_size, void* d_ws, size_t ws_size,
                              hipStream_t stream) {
    const int*   x     = (const int*)  d_in[0];
    const float* emb0  = (const float*)d_in[1];
    const float* emb1  = (const float*)d_in[2];
    const float* emb2  = (const float*)d_in[3];
    const float* W_in  = (const float*)d_in[4];
    const float* b_in  = (const float*)d_in[5];
    const float* W_out = (const float*)d_in[6];
    const float* b_out = (const float*)d_in[7];
    const int*   src0  = (const int*)  d_in[8];
    const int*   src1  = (const int*)  d_in[10];
    float* out = (float*)d_out;

    uchar*  q1       = (uchar*)d_ws;                        // 12.8 MB
    ushort* l2       = (ushort*)(q1 + (size_t)N_NODES * 256);   // 25.6 MB
    uchar*  qy       = (uchar*)(l2 + (size_t)N_NODES * 256);    // 6.4 MB
    float*  rscale1  = (float*)(qy + (size_t)N_NODES * 128);    // 200 KB
    float*  rscale_y = rscale1 + N_NODES;                       // 200 KB
    ushort* W_t      = (ushort*)(rscale_y + N_NODES);           // 128 KB
    ushort* Wo_t     = W_t + 256 * 256;                         // 64 KB

    k_prep<<<384, 256, 0, stream>>>(W_in, W_out, W_t, Wo_t);
    k_encode_mfma<<<(N_NODES + 63) / 64, 256, 0, stream>>>(x, emb0, emb1, emb2, W_t, b_in, q1, rscale1);
    k_hat1_q<<<N_NODES / 16, 256, 0, stream>>>(q1, rscale1, src0, l2);
    k_fc_y<<<(N_NODES + 127) / 128, 256, 0, stream>>>(l2, Wo_t, b_out, qy, rscale_y);
    k_hat2_q<<<N_NODES / 16, 256, 0, stream>>>(qy, rscale_y, src1, out);
}

// Round 10
// 100.686 us; speedup vs baseline: 1.8757x; 1.1563x over previous
//
#include <hip/hip_runtime.h>
#include <math.h>

#define N_NODES 50000
#define DEG 16
#define EPSF 1e-5f

typedef unsigned int uint;
typedef unsigned short ushort;
typedef unsigned char uchar;

using bf16x8 = __attribute__((ext_vector_type(8))) short;
using f32x4  = __attribute__((ext_vector_type(4))) float;

__device__ __forceinline__ uint f2bf_rn(float f) {
    uint u = __float_as_uint(f);
    return (u + 0x7FFFu + ((u >> 16) & 1u)) >> 16;
}
__device__ __forceinline__ uint pack2(float a, float b) {
    return f2bf_rn(a) | (f2bf_rn(b) << 16);
}

// ---- VALU-only wave reductions --------------------------------------------
__device__ __forceinline__ float pl32_max(float v) {
#if __has_builtin(__builtin_amdgcn_permlane32_swap)
    auto r = __builtin_amdgcn_permlane32_swap((int)__float_as_uint(v), (int)__float_as_uint(v), false, false);
    return fmaxf(__uint_as_float((uint)r[0]), __uint_as_float((uint)r[1]));
#else
    return fmaxf(v, __shfl_xor(v, 32, 64));
#endif
}
__device__ __forceinline__ float pl16_max(float v) {
#if __has_builtin(__builtin_amdgcn_permlane16_swap)
    auto r = __builtin_amdgcn_permlane16_swap((int)__float_as_uint(v), (int)__float_as_uint(v), false, false);
    return fmaxf(__uint_as_float((uint)r[0]), __uint_as_float((uint)r[1]));
#else
    return fmaxf(v, __shfl_xor(v, 16, 64));
#endif
}
#define DPP_ROR_ADD(v, CTRL) \
    v += __uint_as_float((uint)__builtin_amdgcn_update_dpp(0, (int)__float_as_uint(v), (CTRL), 0xF, 0xF, false))
#define DPP_ROR_MAX(v, CTRL) \
    v = fmaxf(v, __uint_as_float((uint)__builtin_amdgcn_update_dpp(0, (int)__float_as_uint(v), (CTRL), 0xF, 0xF, false)))

// full sum / max within each 16-lane DPP row (all 16 lanes get the result)
__device__ __forceinline__ float red16_sum(float v) {
    DPP_ROR_ADD(v, 0x121); DPP_ROR_ADD(v, 0x122);
    DPP_ROR_ADD(v, 0x124); DPP_ROR_ADD(v, 0x128);
    return v;
}
__device__ __forceinline__ float red16_max(float v) {
    DPP_ROR_MAX(v, 0x121); DPP_ROR_MAX(v, 0x122);
    DPP_ROR_MAX(v, 0x124); DPP_ROR_MAX(v, 0x128);
    return v;
}

// ---- fast hyperbolic helpers ----------------------------------------------
__device__ __forceinline__ float tanh_over_x(float nm) {      // tanh(nm)/nm, nm>0
    float e = __expf(2.f * nm);
    float t = 1.f - __fdividef(2.f, e + 1.f);
    return __fdividef(t, nm);
}
__device__ __forceinline__ float atanh_over_x(float n) {      // atanh(n)/n, 0<n<1
    float l = __logf(__fdividef(1.f + n, 1.f - n));
    return 0.5f * __fdividef(l, n);
}

// ---- int8 decode: 4 ubytes of dw, acc[i] += ubyte_i * rs ------------------
__device__ __forceinline__ void acc4(float* acc, uint dw, float rs) {
    acc[0] = fmaf((float)(dw & 0xffu),         rs, acc[0]);
    acc[1] = fmaf((float)((dw >> 8) & 0xffu),  rs, acc[1]);
    acc[2] = fmaf((float)((dw >> 16) & 0xffu), rs, acc[2]);
    acc[3] = fmaf((float)(dw >> 24),           rs, acc[3]);
}

// ---------------------------------------------------------------------------
// K0: prep: W_t[n][k]=bf16(W_in[k][n]); Wo_t[n][k]=bf16(W_out[k][n]);
// bf16 copies of emb0/emb1/emb2.
// ---------------------------------------------------------------------------
__global__ __launch_bounds__(256) void k_prep(
    const float* __restrict__ W_in, const float* __restrict__ W_out,
    const float* __restrict__ emb0, const float* __restrict__ emb1,
    const float* __restrict__ emb2,
    ushort* __restrict__ W_t, ushort* __restrict__ Wo_t,
    ushort* __restrict__ e0b, ushort* __restrict__ e1b, ushort* __restrict__ e2b)
{
    const int b = blockIdx.x, t = threadIdx.x;
    if (b < 256) {
        W_t[b * 256 + t] = (ushort)f2bf_rn(W_in[t * 256 + b]);
    } else if (b < 384) {
        const int n = b - 256;
        Wo_t[n * 256 + t] = (ushort)f2bf_rn(W_out[t * 128 + n]);
    } else {
        const int idx = (b - 384) * 256 + t;          // 0 .. 255999
        if (idx < 96000)        e0b[idx] = (ushort)f2bf_rn(emb0[idx]);
        else if (idx < 192000)  e1b[idx - 96000] = (ushort)f2bf_rn(emb1[idx - 96000]);
        else                    e2b[idx - 192000] = (ushort)f2bf_rn(emb2[idx - 192000]);
    }
}

// ---------------------------------------------------------------------------
// K0b: projected tables P_i = emb_i @ W_in[k_i : k_i+K_i, :]   (f32 [1024][256])
// grid = 3 tables x 63 m-tiles of 16 rows; 4 waves x 64-col slices.
// Swapped mfma(wv, f): lane&15 -> row, reg r -> col.
// ---------------------------------------------------------------------------
__global__ __launch_bounds__(256) void k_projtab(
    const ushort* __restrict__ e0b, const ushort* __restrict__ e1b,
    const ushort* __restrict__ e2b, const ushort* __restrict__ W_t,
    float* __restrict__ P0, float* __restrict__ P1, float* __restrict__ P2)
{
    const int tbl = blockIdx.x / 63;
    const int mt  = blockIdx.x % 63;
    const int m0  = mt * 16;

    const ushort* eb = (tbl == 0) ? e0b : (tbl == 1) ? e1b : e2b;
    float* P         = (tbl == 0) ? P0  : (tbl == 1) ? P1  : P2;
    const int KS      = (tbl == 2) ? 2 : 3;          // k-steps of 32
    const int kstride = (tbl == 2) ? 64 : 96;        // row stride in bf16 elems
    const int kofs    = tbl * 96;                    // k offset into W_t rows

    const int lane = threadIdx.x & 63;
    const int w    = threadIdx.x >> 6;
    const int l15  = lane & 15;
    const int lhi  = lane >> 4;

    f32x4 acc[4];
    #pragma unroll
    for (int nf = 0; nf < 4; ++nf) acc[nf] = (f32x4){0.f, 0.f, 0.f, 0.f};

    const int arow = min(m0 + l15, 999);
    const ushort* Ap = eb + (size_t)arow * kstride + lhi * 8;
    const ushort* Wp = W_t + (size_t)(w * 64 + l15) * 256 + kofs + lhi * 8;

    for (int kk = 0; kk < KS; ++kk) {
        bf16x8 f = *(const bf16x8*)(Ap + kk * 32);
        #pragma unroll
        for (int nf = 0; nf < 4; ++nf) {
            bf16x8 wv = *(const bf16x8*)(Wp + (size_t)nf * 16 * 256 + kk * 32);
            acc[nf] = __builtin_amdgcn_mfma_f32_16x16x32_bf16(wv, f, acc[nf], 0, 0, 0);
        }
    }

    const int m = m0 + l15;
    #pragma unroll
    for (int nf = 0; nf < 4; ++nf)
        *(float4*)&P[(size_t)m * 256 + w * 64 + nf * 16 + lhi * 4] =
            *(float4*)&acc[nf];
}

// ---------------------------------------------------------------------------
// K1: encode: t = P0[x0] + P1[x1] + P2[x2] + b_in; quantize rows to biased-u8
// q1 + rscale1. 16-lane group per node, lane owns 16 cols (64 B).
// ---------------------------------------------------------------------------
__global__ __launch_bounds__(256) void k_encode_gather(
    const int* __restrict__ x,
    const float* __restrict__ P0, const float* __restrict__ P1,
    const float* __restrict__ P2, const float* __restrict__ b_in,
    uchar* __restrict__ q1, float* __restrict__ rscale1)
{
    const int tid = threadIdx.x;
    const int gi  = tid >> 4;
    const int p   = tid & 15;
    const int v   = blockIdx.x * 16 + gi;      // 50000 = 3125*16, exact

    const int x0 = x[v * 3 + 0];
    const int x1 = x[v * 3 + 1];
    const int x2 = x[v * 3 + 2];

    const float* p0 = P0 + (size_t)x0 * 256 + p * 16;
    const float* p1 = P1 + (size_t)x1 * 256 + p * 16;
    const float* p2 = P2 + (size_t)x2 * 256 + p * 16;
    const float* bp = b_in + p * 16;

    float tv[16];
    #pragma unroll
    for (int u = 0; u < 4; ++u) {
        float4 a = *(const float4*)(p0 + u * 4);
        float4 c = *(const float4*)(p1 + u * 4);
        float4 d = *(const float4*)(p2 + u * 4);
        float4 bb = *(const float4*)(bp + u * 4);
        tv[u * 4 + 0] = a.x + c.x + d.x + bb.x;
        tv[u * 4 + 1] = a.y + c.y + d.y + bb.y;
        tv[u * 4 + 2] = a.z + c.z + d.z + bb.z;
        tv[u * 4 + 3] = a.w + c.w + d.w + bb.w;
    }

    float lm = 0.f;
    #pragma unroll
    for (int i = 0; i < 16; ++i) lm = fmaxf(lm, fabsf(tv[i]));
    float rm = fmaxf(red16_max(lm), 1e-20f);
    const float qs = __fdividef(127.f, rm);

    uint d[4];
    #pragma unroll
    for (int k = 0; k < 4; ++k) {
        uint b0 = (uint)(int)rintf(fmaf(tv[4 * k + 0], qs, 128.f));
        uint b1 = (uint)(int)rintf(fmaf(tv[4 * k + 1], qs, 128.f));
        uint b2 = (uint)(int)rintf(fmaf(tv[4 * k + 2], qs, 128.f));
        uint b3 = (uint)(int)rintf(fmaf(tv[4 * k + 3], qs, 128.f));
        d[k] = b0 | (b1 << 8) | (b2 << 16) | (b3 << 24);
    }
    uint4 o; o.x = d[0]; o.y = d[1]; o.z = d[2]; o.w = d[3];
    *(uint4*)&q1[(size_t)v * 256 + p * 16] = o;
    if (p == 0) rscale1[v] = rm * (1.f / 127.f);
}

// ---------------------------------------------------------------------------
// K2: hat1: z = mean_17(q1 rows); l2 = log0(relu(exp0(z))) -> bf16 (dense out)
// 16-lane group per node, lane-private accs.
// ---------------------------------------------------------------------------
__global__ __launch_bounds__(256) void k_hat1_q(
    const uchar* __restrict__ q1, const float* __restrict__ rscale1,
    const int* __restrict__ src, ushort* __restrict__ l2)
{
    __shared__ int lsrc[256];
    const int tid = threadIdx.x;
    const int gi  = tid >> 4;
    const int p   = tid & 15;
    const int vb  = blockIdx.x * 16;
    const int v   = vb + gi;

    lsrc[tid] = src[(size_t)vb * DEG + tid];
    __syncthreads();

    float acc[16];
    #pragma unroll
    for (int i = 0; i < 16; i++) acc[i] = 0.f;
    float srs = 0.f;

    #pragma unroll 4
    for (int j = 0; j < DEG; ++j) {
        const int s = lsrc[(gi << 4) | j];
        uint4 r = *(const uint4*)(q1 + ((size_t)s << 8) + p * 16);
        float rs = rscale1[s];
        srs += rs;
        acc4(acc + 0, r.x, rs); acc4(acc + 4, r.y, rs);
        acc4(acc + 8, r.z, rs); acc4(acc + 12, r.w, rs);
    }
    {   // self row
        uint4 r = *(const uint4*)(q1 + ((size_t)v << 8) + p * 16);
        float rs = rscale1[v];
        srs += rs;
        acc4(acc + 0, r.x, rs); acc4(acc + 4, r.y, rs);
        acc4(acc + 8, r.z, rs); acc4(acc + 12, r.w, rs);
    }

    const float inv = 1.f / (float)(DEG + 1);
    const float bias = 128.f * srs;
    float rz[16], ss = 0.f, ssp = 0.f;
    #pragma unroll
    for (int i = 0; i < 16; i++) {
        float z = (acc[i] - bias) * inv;
        ss += z * z;
        rz[i] = fmaxf(z, 0.f);
        ssp += rz[i] * rz[i];
    }
    ss  = red16_sum(ss);
    ssp = red16_sum(ssp);

    float se = tanh_over_x(fmaxf(sqrtf(ss), EPSF));
    float nh = se * sqrtf(ssp);
    float nc = fminf(fmaxf(nh, EPSF), 1.f - EPSF);
    float c  = atanh_over_x(nc) * se;

    uint4 o1, o2;
    o1.x = pack2(c * rz[0],  c * rz[1]);
    o1.y = pack2(c * rz[2],  c * rz[3]);
    o1.z = pack2(c * rz[4],  c * rz[5]);
    o1.w = pack2(c * rz[6],  c * rz[7]);
    o2.x = pack2(c * rz[8],  c * rz[9]);
    o2.y = pack2(c * rz[10], c * rz[11]);
    o2.z = pack2(c * rz[12], c * rz[13]);
    o2.w = pack2(c * rz[14], c * rz[15]);
    ushort* row = l2 + (size_t)v * 256 + p * 16;
    *(uint4*)row = o1;
    *(uint4*)(row + 8) = o2;
}

// ---------------------------------------------------------------------------
// K3: y = l2 @ W_out + b_out (bf16 MFMA, swapped operands), quantized per-row
// to biased-u8 qy (128 B rows) + rscale_y.
// ---------------------------------------------------------------------------
__global__ __launch_bounds__(256) void k_fc_y(
    const ushort* __restrict__ l2, const ushort* __restrict__ Wo_t,
    const float* __restrict__ b_out,
    uchar* __restrict__ qy, float* __restrict__ rscale_y)
{
    const int t    = threadIdx.x;
    const int lane = t & 63;
    const int w    = t >> 6;
    const int l15  = lane & 15;
    const int lhi  = lane >> 4;
    const int m0   = blockIdx.x * 128;

    f32x4 acc[2][8];
    #pragma unroll
    for (int rf = 0; rf < 2; ++rf)
        #pragma unroll
        for (int nf = 0; nf < 8; ++nf)
            acc[rf][nf] = (f32x4){0.f, 0.f, 0.f, 0.f};

    const int ar0 = min(m0 + w * 32 + l15,      N_NODES - 1);
    const int ar1 = min(m0 + w * 32 + 16 + l15, N_NODES - 1);
    const ushort* Ap0 = l2 + (size_t)ar0 * 256 + lhi * 8;
    const ushort* Ap1 = l2 + (size_t)ar1 * 256 + lhi * 8;
    const ushort* Wp  = Wo_t + (size_t)l15 * 256 + lhi * 8;

    for (int kk = 0; kk < 8; ++kk) {
        bf16x8 f0 = *(const bf16x8*)(Ap0 + kk * 32);
        bf16x8 f1 = *(const bf16x8*)(Ap1 + kk * 32);
        #pragma unroll
        for (int nf = 0; nf < 8; ++nf) {
            bf16x8 wv = *(const bf16x8*)(Wp + (size_t)nf * 16 * 256 + kk * 32);
            acc[0][nf] = __builtin_amdgcn_mfma_f32_16x16x32_bf16(wv, f0, acc[0][nf], 0, 0, 0);
            acc[1][nf] = __builtin_amdgcn_mfma_f32_16x16x32_bf16(wv, f1, acc[1][nf], 0, 0, 0);
        }
    }

    float4 bb[8];
    #pragma unroll
    for (int nf = 0; nf < 8; ++nf)
        bb[nf] = *(const float4*)&b_out[nf * 16 + lhi * 4];

    #pragma unroll
    for (int rf = 0; rf < 2; ++rf) {
        const int m = m0 + w * 32 + rf * 16 + l15;
        float lm = 0.f;
        #pragma unroll
        for (int nf = 0; nf < 8; ++nf) {
            float t0 = acc[rf][nf][0] + bb[nf].x;
            float t1 = acc[rf][nf][1] + bb[nf].y;
            float t2 = acc[rf][nf][2] + bb[nf].z;
            float t3 = acc[rf][nf][3] + bb[nf].w;
            acc[rf][nf][0] = t0; acc[rf][nf][1] = t1;
            acc[rf][nf][2] = t2; acc[rf][nf][3] = t3;
            lm = fmaxf(lm, fmaxf(fmaxf(fabsf(t0), fabsf(t1)),
                                 fmaxf(fabsf(t2), fabsf(t3))));
        }
        lm = pl16_max(lm);
        lm = pl32_max(lm);
        lm = fmaxf(lm, 1e-20f);
        const float qs = __fdividef(127.f, lm);
        if (m < N_NODES) {
            #pragma unroll
            for (int nf = 0; nf < 8; ++nf) {
                uint b0 = (uint)(int)rintf(fmaf(acc[rf][nf][0], qs, 128.f));
                uint b1 = (uint)(int)rintf(fmaf(acc[rf][nf][1], qs, 128.f));
                uint b2 = (uint)(int)rintf(fmaf(acc[rf][nf][2], qs, 128.f));
                uint b3 = (uint)(int)rintf(fmaf(acc[rf][nf][3], qs, 128.f));
                *(uint*)&qy[(size_t)m * 128 + nf * 16 + lhi * 4] =
                    b0 | (b1 << 8) | (b2 << 16) | (b3 << 24);
            }
            if (lhi == 0) rscale_y[m] = lm * (1.f / 127.f);
        }
    }
}

// ---------------------------------------------------------------------------
// K4: out = exp0(mean_17(qy rows))   (128 B rows, biased u8)
// 16-lane group per node, lane owns an 8 B chunk -> lane-private accs.
// ---------------------------------------------------------------------------
__global__ __launch_bounds__(256) void k_hat2_q(
    const uchar* __restrict__ qy, const float* __restrict__ rscale_y,
    const int* __restrict__ src, float* __restrict__ out)
{
    __shared__ int lsrc[256];
    const int tid = threadIdx.x;
    const int gi  = tid >> 4;
    const int p   = tid & 15;           // 8 B chunk within 128 B row
    const int vb  = blockIdx.x * 16;
    const int v   = vb + gi;

    lsrc[tid] = src[(size_t)vb * DEG + tid];
    __syncthreads();

    float acc[8];
    #pragma unroll
    for (int i = 0; i < 8; i++) acc[i] = 0.f;
    float srs = 0.f;

    #pragma unroll 4
    for (int j = 0; j < DEG; ++j) {
        const int s = lsrc[(gi << 4) | j];
        uint2 r = *(const uint2*)(qy + ((size_t)s << 7) + p * 8);
        float rs = rscale_y[s];
        srs += rs;
        acc4(acc + 0, r.x, rs); acc4(acc + 4, r.y, rs);
    }
    {   // self row
        uint2 r = *(const uint2*)(qy + ((size_t)v << 7) + p * 8);
        float rs = rscale_y[v];
        srs += rs;
        acc4(acc + 0, r.x, rs); acc4(acc + 4, r.y, rs);
    }

    const float inv = 1.f / (float)(DEG + 1);
    const float bias = 128.f * srs;
    float z[8], ss = 0.f;
    #pragma unroll
    for (int i = 0; i < 8; i++) {
        z[i] = (acc[i] - bias) * inv;
        ss += z[i] * z[i];
    }
    ss = red16_sum(ss);

    float se = tanh_over_x(fmaxf(sqrtf(ss), EPSF));

    float4 o0, o1;
    o0.x = se * z[0]; o0.y = se * z[1]; o0.z = se * z[2]; o0.w = se * z[3];
    o1.x = se * z[4]; o1.y = se * z[5]; o1.z = se * z[6]; o1.w = se * z[7];
    float* row = out + (size_t)v * 128 + p * 8;
    *(float4*)row = o0;
    *(float4*)(row + 4) = o1;
}

extern "C" void kernel_launch(void* const* d_in, const int* in_sizes, int n_in,
                              void* d_out, int out_size, void* d_ws, size_t ws_size,
                              hipStream_t stream) {
    const int*   x     = (const int*)  d_in[0];
    const float* emb0  = (const float*)d_in[1];
    const float* emb1  = (const float*)d_in[2];
    const float* emb2  = (const float*)d_in[3];
    const float* W_in  = (const float*)d_in[4];
    const float* b_in  = (const float*)d_in[5];
    const float* W_out = (const float*)d_in[6];
    const float* b_out = (const float*)d_in[7];
    const int*   src0  = (const int*)  d_in[8];
    const int*   src1  = (const int*)  d_in[10];
    float* out = (float*)d_out;

    uchar*  q1       = (uchar*)d_ws;                            // 12.8 MB
    ushort* l2       = (ushort*)(q1 + (size_t)N_NODES * 256);   // 25.6 MB
    uchar*  qy       = (uchar*)(l2 + (size_t)N_NODES * 256);    // 6.4 MB
    float*  rscale1  = (float*)(qy + (size_t)N_NODES * 128);    // 200 KB
    float*  rscale_y = rscale1 + N_NODES;                       // 200 KB
    ushort* W_t      = (ushort*)(rscale_y + N_NODES);           // 128 KB
    ushort* Wo_t     = W_t + 256 * 256;                         // 64 KB
    ushort* e0b      = Wo_t + 128 * 256;                        // 192 KB
    ushort* e1b      = e0b + 1000 * 96;                         // 192 KB
    ushort* e2b      = e1b + 1000 * 96;                         // 128 KB
    float*  P0       = (float*)(e2b + 1000 * 64);               // 1 MB (1024 rows)
    float*  P1       = P0 + 1024 * 256;                         // 1 MB
    float*  P2       = P1 + 1024 * 256;                         // 1 MB

    k_prep<<<1384, 256, 0, stream>>>(W_in, W_out, emb0, emb1, emb2,
                                     W_t, Wo_t, e0b, e1b, e2b);
    k_projtab<<<189, 256, 0, stream>>>(e0b, e1b, e2b, W_t, P0, P1, P2);
    k_encode_gather<<<N_NODES / 16, 256, 0, stream>>>(x, P0, P1, P2, b_in, q1, rscale1);
    k_hat1_q<<<N_NODES / 16, 256, 0, stream>>>(q1, rscale1, src0, l2);
    k_fc_y<<<(N_NODES + 127) / 128, 256, 0, stream>>>(l2, Wo_t, b_out, qy, rscale_y);
    k_hat2_q<<<N_NODES / 16, 256, 0, stream>>>(qy, rscale_y, src1, out);
}

// Round 11
// 92.001 us; speedup vs baseline: 2.0528x; 1.0944x over previous
//
#include <hip/hip_runtime.h>
#include <math.h>

#define N_NODES 50000
#define DEG 16
#define EPSF 1e-5f

typedef unsigned int uint;
typedef unsigned short ushort;
typedef unsigned char uchar;

using bf16x8 = __attribute__((ext_vector_type(8))) short;
using f32x4  = __attribute__((ext_vector_type(4))) float;

__device__ __forceinline__ uint f2bf_rn(float f) {
    uint u = __float_as_uint(f);
    return (u + 0x7FFFu + ((u >> 16) & 1u)) >> 16;
}
__device__ __forceinline__ uint pack2(float a, float b) {
    return f2bf_rn(a) | (f2bf_rn(b) << 16);
}

// ---- VALU-only wave reductions --------------------------------------------
__device__ __forceinline__ float pl32_max(float v) {
#if __has_builtin(__builtin_amdgcn_permlane32_swap)
    auto r = __builtin_amdgcn_permlane32_swap((int)__float_as_uint(v), (int)__float_as_uint(v), false, false);
    return fmaxf(__uint_as_float((uint)r[0]), __uint_as_float((uint)r[1]));
#else
    return fmaxf(v, __shfl_xor(v, 32, 64));
#endif
}
__device__ __forceinline__ float pl16_max(float v) {
#if __has_builtin(__builtin_amdgcn_permlane16_swap)
    auto r = __builtin_amdgcn_permlane16_swap((int)__float_as_uint(v), (int)__float_as_uint(v), false, false);
    return fmaxf(__uint_as_float((uint)r[0]), __uint_as_float((uint)r[1]));
#else
    return fmaxf(v, __shfl_xor(v, 16, 64));
#endif
}
#define DPP_ROR_ADD(v, CTRL) \
    v += __uint_as_float((uint)__builtin_amdgcn_update_dpp(0, (int)__float_as_uint(v), (CTRL), 0xF, 0xF, false))
#define DPP_ROR_MAX(v, CTRL) \
    v = fmaxf(v, __uint_as_float((uint)__builtin_amdgcn_update_dpp(0, (int)__float_as_uint(v), (CTRL), 0xF, 0xF, false)))

// full sum / max within each 16-lane DPP row (all 16 lanes get the result)
__device__ __forceinline__ float red16_sum(float v) {
    DPP_ROR_ADD(v, 0x121); DPP_ROR_ADD(v, 0x122);
    DPP_ROR_ADD(v, 0x124); DPP_ROR_ADD(v, 0x128);
    return v;
}
__device__ __forceinline__ float red16_max(float v) {
    DPP_ROR_MAX(v, 0x121); DPP_ROR_MAX(v, 0x122);
    DPP_ROR_MAX(v, 0x124); DPP_ROR_MAX(v, 0x128);
    return v;
}

// ---- fast hyperbolic helpers ----------------------------------------------
__device__ __forceinline__ float tanh_over_x(float nm) {      // tanh(nm)/nm, nm>0
    float e = __expf(2.f * nm);
    float t = 1.f - __fdividef(2.f, e + 1.f);
    return __fdividef(t, nm);
}
__device__ __forceinline__ float atanh_over_x(float n) {      // atanh(n)/n, 0<n<1
    float l = __logf(__fdividef(1.f + n, 1.f - n));
    return 0.5f * __fdividef(l, n);
}

// ---- int8 decode: 4 ubytes of dw, acc[i] += ubyte_i * rs ------------------
__device__ __forceinline__ void acc4(float* acc, uint dw, float rs) {
    acc[0] = fmaf((float)(dw & 0xffu),         rs, acc[0]);
    acc[1] = fmaf((float)((dw >> 8) & 0xffu),  rs, acc[1]);
    acc[2] = fmaf((float)((dw >> 16) & 0xffu), rs, acc[2]);
    acc[3] = fmaf((float)(dw >> 24),           rs, acc[3]);
}

// ---------------------------------------------------------------------------
// K0: prep: W_t[n][k]=bf16(W_in[k][n]); Wo_t[n][k]=bf16(W_out[k][n])
// ---------------------------------------------------------------------------
__global__ __launch_bounds__(256) void k_prep(
    const float* __restrict__ W_in, const float* __restrict__ W_out,
    ushort* __restrict__ W_t, ushort* __restrict__ Wo_t)
{
    const int b = blockIdx.x, t = threadIdx.x;
    if (b < 256) {
        W_t[b * 256 + t] = (ushort)f2bf_rn(W_in[t * 256 + b]);
    } else {
        const int n = b - 256;
        Wo_t[n * 256 + t] = (ushort)f2bf_rn(W_out[t * 128 + n]);
    }
}

// ---------------------------------------------------------------------------
// K0b: projected tables P_i = emb_i @ W_in[k_i : k_i+K_i, :]   (f32 [1024][256])
// grid = 3 tables x 63 m-tiles of 16 rows; 4 waves x 64-col slices.
// A-fragments converted f32->bf16 inline from emb (no staging).
// ---------------------------------------------------------------------------
__global__ __launch_bounds__(256) void k_projtab(
    const float* __restrict__ emb0, const float* __restrict__ emb1,
    const float* __restrict__ emb2, const ushort* __restrict__ W_t,
    float* __restrict__ P0, float* __restrict__ P1, float* __restrict__ P2)
{
    const int tbl = blockIdx.x / 63;
    const int mt  = blockIdx.x % 63;
    const int m0  = mt * 16;

    const float* eb = (tbl == 0) ? emb0 : (tbl == 1) ? emb1 : emb2;
    float* P        = (tbl == 0) ? P0   : (tbl == 1) ? P1   : P2;
    const int KS      = (tbl == 2) ? 2 : 3;          // k-steps of 32
    const int kstride = (tbl == 2) ? 64 : 96;        // row stride in f32 elems
    const int kofs    = tbl * 96;                    // k offset into W_t rows

    const int lane = threadIdx.x & 63;
    const int w    = threadIdx.x >> 6;
    const int l15  = lane & 15;
    const int lhi  = lane >> 4;

    f32x4 acc[4];
    #pragma unroll
    for (int nf = 0; nf < 4; ++nf) acc[nf] = (f32x4){0.f, 0.f, 0.f, 0.f};

    const int arow = min(m0 + l15, 999);
    const float* Ap  = eb + (size_t)arow * kstride + lhi * 8;
    const ushort* Wp = W_t + (size_t)(w * 64 + l15) * 256 + kofs + lhi * 8;

    for (int kk = 0; kk < KS; ++kk) {
        float4 v0 = *(const float4*)(Ap + kk * 32);
        float4 v1 = *(const float4*)(Ap + kk * 32 + 4);
        union { uint4 u; bf16x8 b; } cv;
        cv.u.x = pack2(v0.x, v0.y); cv.u.y = pack2(v0.z, v0.w);
        cv.u.z = pack2(v1.x, v1.y); cv.u.w = pack2(v1.z, v1.w);
        bf16x8 f = cv.b;
        #pragma unroll
        for (int nf = 0; nf < 4; ++nf) {
            bf16x8 wv = *(const bf16x8*)(Wp + (size_t)nf * 16 * 256 + kk * 32);
            acc[nf] = __builtin_amdgcn_mfma_f32_16x16x32_bf16(wv, f, acc[nf], 0, 0, 0);
        }
    }

    const int m = m0 + l15;
    #pragma unroll
    for (int nf = 0; nf < 4; ++nf)
        *(float4*)&P[(size_t)m * 256 + w * 64 + nf * 16 + lhi * 4] =
            *(float4*)&acc[nf];
}

// ---------------------------------------------------------------------------
// K1: encode: t = P0[x0] + P1[x1] + P2[x2] + b_in; quantize rows to biased-u8
// q1 + rscale1. 16-lane group per node, lane owns 16 cols (64 B).
// ---------------------------------------------------------------------------
__global__ __launch_bounds__(256) void k_encode_gather(
    const int* __restrict__ x,
    const float* __restrict__ P0, const float* __restrict__ P1,
    const float* __restrict__ P2, const float* __restrict__ b_in,
    uchar* __restrict__ q1, float* __restrict__ rscale1)
{
    const int tid = threadIdx.x;
    const int gi  = tid >> 4;
    const int p   = tid & 15;
    const int v   = blockIdx.x * 16 + gi;      // 50000 = 3125*16, exact

    const int x0 = x[v * 3 + 0];
    const int x1 = x[v * 3 + 1];
    const int x2 = x[v * 3 + 2];

    const float* p0 = P0 + (size_t)x0 * 256 + p * 16;
    const float* p1 = P1 + (size_t)x1 * 256 + p * 16;
    const float* p2 = P2 + (size_t)x2 * 256 + p * 16;
    const float* bp = b_in + p * 16;

    float tv[16];
    #pragma unroll
    for (int u = 0; u < 4; ++u) {
        float4 a = *(const float4*)(p0 + u * 4);
        float4 c = *(const float4*)(p1 + u * 4);
        float4 d = *(const float4*)(p2 + u * 4);
        float4 bb = *(const float4*)(bp + u * 4);
        tv[u * 4 + 0] = a.x + c.x + d.x + bb.x;
        tv[u * 4 + 1] = a.y + c.y + d.y + bb.y;
        tv[u * 4 + 2] = a.z + c.z + d.z + bb.z;
        tv[u * 4 + 3] = a.w + c.w + d.w + bb.w;
    }

    float lm = 0.f;
    #pragma unroll
    for (int i = 0; i < 16; ++i) lm = fmaxf(lm, fabsf(tv[i]));
    float rm = fmaxf(red16_max(lm), 1e-20f);
    const float qs = __fdividef(127.f, rm);

    uint d[4];
    #pragma unroll
    for (int k = 0; k < 4; ++k) {
        uint b0 = (uint)(int)rintf(fmaf(tv[4 * k + 0], qs, 128.f));
        uint b1 = (uint)(int)rintf(fmaf(tv[4 * k + 1], qs, 128.f));
        uint b2 = (uint)(int)rintf(fmaf(tv[4 * k + 2], qs, 128.f));
        uint b3 = (uint)(int)rintf(fmaf(tv[4 * k + 3], qs, 128.f));
        d[k] = b0 | (b1 << 8) | (b2 << 16) | (b3 << 24);
    }
    uint4 o; o.x = d[0]; o.y = d[1]; o.z = d[2]; o.w = d[3];
    *(uint4*)&q1[(size_t)v * 256 + p * 16] = o;
    if (p == 0) rscale1[v] = rm * (1.f / 127.f);
}

// ---------------------------------------------------------------------------
// K2: FUSED hat1 + fc_out-projection:
//   Phase A: z = mean_17(q1 rows); l2 = log0(relu(exp0(z))) -> bf16 tile in LDS
//   Phase B: y = l2_tile @ W_out + b_out (MFMA), quantize per-row -> qy
// Block = 256 thr = 16 nodes; lane-private accs in phase A.
// ---------------------------------------------------------------------------
__global__ __launch_bounds__(256) void k_hat1_fc(
    const uchar* __restrict__ q1, const float* __restrict__ rscale1,
    const int* __restrict__ src,
    const ushort* __restrict__ Wo_t, const float* __restrict__ b_out,
    uchar* __restrict__ qy, float* __restrict__ rscale_y)
{
    __shared__ int lsrc[256];
    __shared__ ushort T[16][264];        // 16 l2 rows, +8 pad
    __shared__ float smaxq[4][16];

    const int tid = threadIdx.x;
    const int gi  = tid >> 4;           // node within block
    const int p   = tid & 15;           // 16-col chunk
    const int vb  = blockIdx.x * 16;
    const int v   = vb + gi;

    lsrc[tid] = src[(size_t)vb * DEG + tid];
    __syncthreads();

    // ---- phase A: gather-mean + nonlinearity (lane-private) ----
    float acc[16];
    #pragma unroll
    for (int i = 0; i < 16; i++) acc[i] = 0.f;
    float srs = 0.f;

    #pragma unroll 4
    for (int j = 0; j < DEG; ++j) {
        const int s = lsrc[(gi << 4) | j];
        uint4 r = *(const uint4*)(q1 + ((size_t)s << 8) + p * 16);
        float rs = rscale1[s];
        srs += rs;
        acc4(acc + 0, r.x, rs); acc4(acc + 4, r.y, rs);
        acc4(acc + 8, r.z, rs); acc4(acc + 12, r.w, rs);
    }
    {   // self row
        uint4 r = *(const uint4*)(q1 + ((size_t)v << 8) + p * 16);
        float rs = rscale1[v];
        srs += rs;
        acc4(acc + 0, r.x, rs); acc4(acc + 4, r.y, rs);
        acc4(acc + 8, r.z, rs); acc4(acc + 12, r.w, rs);
    }

    const float inv = 1.f / (float)(DEG + 1);
    const float bias = 128.f * srs;
    float rz[16], ss = 0.f, ssp = 0.f;
    #pragma unroll
    for (int i = 0; i < 16; i++) {
        float z = (acc[i] - bias) * inv;
        ss += z * z;
        rz[i] = fmaxf(z, 0.f);
        ssp += rz[i] * rz[i];
    }
    ss  = red16_sum(ss);
    ssp = red16_sum(ssp);

    float se = tanh_over_x(fmaxf(sqrtf(ss), EPSF));
    float nh = se * sqrtf(ssp);
    float nc = fminf(fmaxf(nh, EPSF), 1.f - EPSF);
    float c  = atanh_over_x(nc) * se;

    uint4 o1, o2;
    o1.x = pack2(c * rz[0],  c * rz[1]);
    o1.y = pack2(c * rz[2],  c * rz[3]);
    o1.z = pack2(c * rz[4],  c * rz[5]);
    o1.w = pack2(c * rz[6],  c * rz[7]);
    o2.x = pack2(c * rz[8],  c * rz[9]);
    o2.y = pack2(c * rz[10], c * rz[11]);
    o2.z = pack2(c * rz[12], c * rz[13]);
    o2.w = pack2(c * rz[14], c * rz[15]);
    *(uint4*)&T[gi][p * 16]     = o1;
    *(uint4*)&T[gi][p * 16 + 8] = o2;
    __syncthreads();

    // ---- phase B: y = T @ W_out + b_out, quantize -> qy ----
    const int lane = tid & 63;
    const int w    = tid >> 6;
    const int l15  = lane & 15;          // node
    const int lhi  = lane >> 4;

    f32x4 facc[2];
    facc[0] = (f32x4){0.f, 0.f, 0.f, 0.f};
    facc[1] = (f32x4){0.f, 0.f, 0.f, 0.f};

    const ushort* Wp = Wo_t + (size_t)(w * 2 * 16 + l15) * 256 + lhi * 8;

    for (int kk = 0; kk < 8; ++kk) {
        bf16x8 f = *(const bf16x8*)&T[l15][kk * 32 + lhi * 8];
        #pragma unroll
        for (int nf = 0; nf < 2; ++nf) {
            bf16x8 wv = *(const bf16x8*)(Wp + (size_t)nf * 16 * 256 + kk * 32);
            facc[nf] = __builtin_amdgcn_mfma_f32_16x16x32_bf16(wv, f, facc[nf], 0, 0, 0);
        }
    }

    float lm = 0.f;
    #pragma unroll
    for (int nf = 0; nf < 2; ++nf) {
        float4 bb = *(const float4*)&b_out[(w * 2 + nf) * 16 + lhi * 4];
        facc[nf][0] += bb.x; facc[nf][1] += bb.y;
        facc[nf][2] += bb.z; facc[nf][3] += bb.w;
        lm = fmaxf(lm, fmaxf(fmaxf(fabsf(facc[nf][0]), fabsf(facc[nf][1])),
                             fmaxf(fabsf(facc[nf][2]), fabsf(facc[nf][3]))));
    }
    lm = pl16_max(lm);       // combine lhi pairs
    lm = pl32_max(lm);       // -> max over all lhi for this (w, l15)
    if (lhi == 0) smaxq[w][l15] = lm;
    __syncthreads();

    float rm = fmaxf(fmaxf(smaxq[0][l15], smaxq[1][l15]),
                     fmaxf(smaxq[2][l15], smaxq[3][l15]));
    rm = fmaxf(rm, 1e-20f);
    const float qs = __fdividef(127.f, rm);
    const int node = vb + l15;

    #pragma unroll
    for (int nf = 0; nf < 2; ++nf) {
        uint b0 = (uint)(int)rintf(fmaf(facc[nf][0], qs, 128.f));
        uint b1 = (uint)(int)rintf(fmaf(facc[nf][1], qs, 128.f));
        uint b2 = (uint)(int)rintf(fmaf(facc[nf][2], qs, 128.f));
        uint b3 = (uint)(int)rintf(fmaf(facc[nf][3], qs, 128.f));
        *(uint*)&qy[(size_t)node * 128 + (w * 2 + nf) * 16 + lhi * 4] =
            b0 | (b1 << 8) | (b2 << 16) | (b3 << 24);
    }
    if (tid < 16) rscale_y[vb + tid] = rm * (1.f / 127.f);
}

// ---------------------------------------------------------------------------
// K3: out = exp0(mean_17(qy rows))   (128 B rows, biased u8)
// 16-lane group per node, lane owns an 8 B chunk -> lane-private accs.
// ---------------------------------------------------------------------------
__global__ __launch_bounds__(256) void k_hat2_q(
    const uchar* __restrict__ qy, const float* __restrict__ rscale_y,
    const int* __restrict__ src, float* __restrict__ out)
{
    __shared__ int lsrc[256];
    const int tid = threadIdx.x;
    const int gi  = tid >> 4;
    const int p   = tid & 15;           // 8 B chunk within 128 B row
    const int vb  = blockIdx.x * 16;
    const int v   = vb + gi;

    lsrc[tid] = src[(size_t)vb * DEG + tid];
    __syncthreads();

    float acc[8];
    #pragma unroll
    for (int i = 0; i < 8; i++) acc[i] = 0.f;
    float srs = 0.f;

    #pragma unroll 4
    for (int j = 0; j < DEG; ++j) {
        const int s = lsrc[(gi << 4) | j];
        uint2 r = *(const uint2*)(qy + ((size_t)s << 7) + p * 8);
        float rs = rscale_y[s];
        srs += rs;
        acc4(acc + 0, r.x, rs); acc4(acc + 4, r.y, rs);
    }
    {   // self row
        uint2 r = *(const uint2*)(qy + ((size_t)v << 7) + p * 8);
        float rs = rscale_y[v];
        srs += rs;
        acc4(acc + 0, r.x, rs); acc4(acc + 4, r.y, rs);
    }

    const float inv = 1.f / (float)(DEG + 1);
    const float bias = 128.f * srs;
    float z[8], ss = 0.f;
    #pragma unroll
    for (int i = 0; i < 8; i++) {
        z[i] = (acc[i] - bias) * inv;
        ss += z[i] * z[i];
    }
    ss = red16_sum(ss);

    float se = tanh_over_x(fmaxf(sqrtf(ss), EPSF));

    float4 o0, o1;
    o0.x = se * z[0]; o0.y = se * z[1]; o0.z = se * z[2]; o0.w = se * z[3];
    o1.x = se * z[4]; o1.y = se * z[5]; o1.z = se * z[6]; o1.w = se * z[7];
    float* row = out + (size_t)v * 128 + p * 8;
    *(float4*)row = o0;
    *(float4*)(row + 4) = o1;
}

extern "C" void kernel_launch(void* const* d_in, const int* in_sizes, int n_in,
                              void* d_out, int out_size, void* d_ws, size_t ws_size,
                              hipStream_t stream) {
    const int*   x     = (const int*)  d_in[0];
    const float* emb0  = (const float*)d_in[1];
    const float* emb1  = (const float*)d_in[2];
    const float* emb2  = (const float*)d_in[3];
    const float* W_in  = (const float*)d_in[4];
    const float* b_in  = (const float*)d_in[5];
    const float* W_out = (const float*)d_in[6];
    const float* b_out = (const float*)d_in[7];
    const int*   src0  = (const int*)  d_in[8];
    const int*   src1  = (const int*)  d_in[10];
    float* out = (float*)d_out;

    uchar*  q1       = (uchar*)d_ws;                            // 12.8 MB
    uchar*  qy       = q1 + (size_t)N_NODES * 256;              // 6.4 MB
    float*  rscale1  = (float*)(qy + (size_t)N_NODES * 128);    // 200 KB
    float*  rscale_y = rscale1 + N_NODES;                       // 200 KB
    ushort* W_t      = (ushort*)(rscale_y + N_NODES);           // 128 KB
    ushort* Wo_t     = W_t + 256 * 256;                         // 64 KB
    float*  P0       = (float*)(Wo_t + 128 * 256);              // 1 MB (1024 rows)
    float*  P1       = P0 + 1024 * 256;                         // 1 MB
    float*  P2       = P1 + 1024 * 256;                         // 1 MB

    k_prep<<<384, 256, 0, stream>>>(W_in, W_out, W_t, Wo_t);
    k_projtab<<<189, 256, 0, stream>>>(emb0, emb1, emb2, W_t, P0, P1, P2);
    k_encode_gather<<<N_NODES / 16, 256, 0, stream>>>(x, P0, P1, P2, b_in, q1, rscale1);
    k_hat1_fc<<<N_NODES / 16, 256, 0, stream>>>(q1, rscale1, src0, Wo_t, b_out, qy, rscale_y);
    k_hat2_q<<<N_NODES / 16, 256, 0, stream>>>(qy, rscale_y, src1, out);
}

// Round 12
// 88.286 us; speedup vs baseline: 2.1392x; 1.0421x over previous
//
#include <hip/hip_runtime.h>
#include <math.h>

#define N_NODES 50000
#define DEG 16
#define EPSF 1e-5f

typedef unsigned int uint;
typedef unsigned short ushort;
typedef unsigned char uchar;

using bf16x8 = __attribute__((ext_vector_type(8))) short;
using f32x4  = __attribute__((ext_vector_type(4))) float;

__device__ __forceinline__ uint f2bf_rn(float f) {
    uint u = __float_as_uint(f);
    return (u + 0x7FFFu + ((u >> 16) & 1u)) >> 16;
}
__device__ __forceinline__ uint pack2(float a, float b) {
    return f2bf_rn(a) | (f2bf_rn(b) << 16);
}

// ---- VALU-only wave reductions --------------------------------------------
__device__ __forceinline__ float pl32_max(float v) {
#if __has_builtin(__builtin_amdgcn_permlane32_swap)
    auto r = __builtin_amdgcn_permlane32_swap((int)__float_as_uint(v), (int)__float_as_uint(v), false, false);
    return fmaxf(__uint_as_float((uint)r[0]), __uint_as_float((uint)r[1]));
#else
    return fmaxf(v, __shfl_xor(v, 32, 64));
#endif
}
__device__ __forceinline__ float pl16_max(float v) {
#if __has_builtin(__builtin_amdgcn_permlane16_swap)
    auto r = __builtin_amdgcn_permlane16_swap((int)__float_as_uint(v), (int)__float_as_uint(v), false, false);
    return fmaxf(__uint_as_float((uint)r[0]), __uint_as_float((uint)r[1]));
#else
    return fmaxf(v, __shfl_xor(v, 16, 64));
#endif
}
#define DPP_ROR_ADD(v, CTRL) \
    v += __uint_as_float((uint)__builtin_amdgcn_update_dpp(0, (int)__float_as_uint(v), (CTRL), 0xF, 0xF, false))
#define DPP_ROR_MAX(v, CTRL) \
    v = fmaxf(v, __uint_as_float((uint)__builtin_amdgcn_update_dpp(0, (int)__float_as_uint(v), (CTRL), 0xF, 0xF, false)))

// full sum / max within each 16-lane DPP row (all 16 lanes get the result)
__device__ __forceinline__ float red16_sum(float v) {
    DPP_ROR_ADD(v, 0x121); DPP_ROR_ADD(v, 0x122);
    DPP_ROR_ADD(v, 0x124); DPP_ROR_ADD(v, 0x128);
    return v;
}
__device__ __forceinline__ float red16_max(float v) {
    DPP_ROR_MAX(v, 0x121); DPP_ROR_MAX(v, 0x122);
    DPP_ROR_MAX(v, 0x124); DPP_ROR_MAX(v, 0x128);
    return v;
}

// ---- fast hyperbolic helpers ----------------------------------------------
__device__ __forceinline__ float tanh_over_x(float nm) {      // tanh(nm)/nm, nm>0
    float e = __expf(2.f * nm);
    float t = 1.f - __fdividef(2.f, e + 1.f);
    return __fdividef(t, nm);
}
__device__ __forceinline__ float atanh_over_x(float n) {      // atanh(n)/n, 0<n<1
    float l = __logf(__fdividef(1.f + n, 1.f - n));
    return 0.5f * __fdividef(l, n);
}

// ---- int8 decode: 4 ubytes of dw, acc[i] += ubyte_i * rs ------------------
__device__ __forceinline__ void acc4(float* acc, uint dw, float rs) {
    acc[0] = fmaf((float)(dw & 0xffu),         rs, acc[0]);
    acc[1] = fmaf((float)((dw >> 8) & 0xffu),  rs, acc[1]);
    acc[2] = fmaf((float)((dw >> 16) & 0xffu), rs, acc[2]);
    acc[3] = fmaf((float)(dw >> 24),           rs, acc[3]);
}
__device__ __forceinline__ void acc16(float* acc, uint4 r, float rs) {
    acc4(acc + 0, r.x, rs); acc4(acc + 4, r.y, rs);
    acc4(acc + 8, r.z, rs); acc4(acc + 12, r.w, rs);
}

// ---------------------------------------------------------------------------
// K0: prep: W_t[n][k]=bf16(W_in[k][n]); Wo_t[n][k]=bf16(W_out[k][n])
// ---------------------------------------------------------------------------
__global__ __launch_bounds__(256) void k_prep(
    const float* __restrict__ W_in, const float* __restrict__ W_out,
    ushort* __restrict__ W_t, ushort* __restrict__ Wo_t)
{
    const int b = blockIdx.x, t = threadIdx.x;
    if (b < 256) {
        W_t[b * 256 + t] = (ushort)f2bf_rn(W_in[t * 256 + b]);
    } else {
        const int n = b - 256;
        Wo_t[n * 256 + t] = (ushort)f2bf_rn(W_out[t * 128 + n]);
    }
}

// ---------------------------------------------------------------------------
// K0b: projected tables P_i = emb_i @ W_in[k_i : k_i+K_i, :]   (f32 [1024][256])
// ---------------------------------------------------------------------------
__global__ __launch_bounds__(256) void k_projtab(
    const float* __restrict__ emb0, const float* __restrict__ emb1,
    const float* __restrict__ emb2, const ushort* __restrict__ W_t,
    float* __restrict__ P0, float* __restrict__ P1, float* __restrict__ P2)
{
    const int tbl = blockIdx.x / 63;
    const int mt  = blockIdx.x % 63;
    const int m0  = mt * 16;

    const float* eb = (tbl == 0) ? emb0 : (tbl == 1) ? emb1 : emb2;
    float* P        = (tbl == 0) ? P0   : (tbl == 1) ? P1   : P2;
    const int KS      = (tbl == 2) ? 2 : 3;          // k-steps of 32
    const int kstride = (tbl == 2) ? 64 : 96;        // row stride in f32 elems
    const int kofs    = tbl * 96;                    // k offset into W_t rows

    const int lane = threadIdx.x & 63;
    const int w    = threadIdx.x >> 6;
    const int l15  = lane & 15;
    const int lhi  = lane >> 4;

    f32x4 acc[4];
    #pragma unroll
    for (int nf = 0; nf < 4; ++nf) acc[nf] = (f32x4){0.f, 0.f, 0.f, 0.f};

    const int arow = min(m0 + l15, 999);
    const float* Ap  = eb + (size_t)arow * kstride + lhi * 8;
    const ushort* Wp = W_t + (size_t)(w * 64 + l15) * 256 + kofs + lhi * 8;

    for (int kk = 0; kk < KS; ++kk) {
        float4 v0 = *(const float4*)(Ap + kk * 32);
        float4 v1 = *(const float4*)(Ap + kk * 32 + 4);
        union { uint4 u; bf16x8 b; } cv;
        cv.u.x = pack2(v0.x, v0.y); cv.u.y = pack2(v0.z, v0.w);
        cv.u.z = pack2(v1.x, v1.y); cv.u.w = pack2(v1.z, v1.w);
        bf16x8 f = cv.b;
        #pragma unroll
        for (int nf = 0; nf < 4; ++nf) {
            bf16x8 wv = *(const bf16x8*)(Wp + (size_t)nf * 16 * 256 + kk * 32);
            acc[nf] = __builtin_amdgcn_mfma_f32_16x16x32_bf16(wv, f, acc[nf], 0, 0, 0);
        }
    }

    const int m = m0 + l15;
    #pragma unroll
    for (int nf = 0; nf < 4; ++nf)
        *(float4*)&P[(size_t)m * 256 + w * 64 + nf * 16 + lhi * 4] =
            *(float4*)&acc[nf];
}

// ---------------------------------------------------------------------------
// K1: encode: t = P0[x0] + P1[x1] + P2[x2] + b_in; quantize rows to biased-u8
// q1 + rscale1. 16-lane group per node, lane owns 16 cols (64 B).
// ---------------------------------------------------------------------------
__global__ __launch_bounds__(256) void k_encode_gather(
    const int* __restrict__ x,
    const float* __restrict__ P0, const float* __restrict__ P1,
    const float* __restrict__ P2, const float* __restrict__ b_in,
    uchar* __restrict__ q1, float* __restrict__ rscale1)
{
    const int tid = threadIdx.x;
    const int gi  = tid >> 4;
    const int p   = tid & 15;
    const int v   = blockIdx.x * 16 + gi;      // 50000 = 3125*16, exact

    const int x0 = x[v * 3 + 0];
    const int x1 = x[v * 3 + 1];
    const int x2 = x[v * 3 + 2];

    const float* p0 = P0 + (size_t)x0 * 256 + p * 16;
    const float* p1 = P1 + (size_t)x1 * 256 + p * 16;
    const float* p2 = P2 + (size_t)x2 * 256 + p * 16;
    const float* bp = b_in + p * 16;

    float tv[16];
    #pragma unroll
    for (int u = 0; u < 4; ++u) {
        float4 a = *(const float4*)(p0 + u * 4);
        float4 c = *(const float4*)(p1 + u * 4);
        float4 d = *(const float4*)(p2 + u * 4);
        float4 bb = *(const float4*)(bp + u * 4);
        tv[u * 4 + 0] = a.x + c.x + d.x + bb.x;
        tv[u * 4 + 1] = a.y + c.y + d.y + bb.y;
        tv[u * 4 + 2] = a.z + c.z + d.z + bb.z;
        tv[u * 4 + 3] = a.w + c.w + d.w + bb.w;
    }

    float lm = 0.f;
    #pragma unroll
    for (int i = 0; i < 16; ++i) lm = fmaxf(lm, fabsf(tv[i]));
    float rm = fmaxf(red16_max(lm), 1e-20f);
    const float qs = __fdividef(127.f, rm);

    uint d[4];
    #pragma unroll
    for (int k = 0; k < 4; ++k) {
        uint b0 = (uint)(int)rintf(fmaf(tv[4 * k + 0], qs, 128.f));
        uint b1 = (uint)(int)rintf(fmaf(tv[4 * k + 1], qs, 128.f));
        uint b2 = (uint)(int)rintf(fmaf(tv[4 * k + 2], qs, 128.f));
        uint b3 = (uint)(int)rintf(fmaf(tv[4 * k + 3], qs, 128.f));
        d[k] = b0 | (b1 << 8) | (b2 << 16) | (b3 << 24);
    }
    uint4 o; o.x = d[0]; o.y = d[1]; o.z = d[2]; o.w = d[3];
    *(uint4*)&q1[(size_t)v * 256 + p * 16] = o;
    if (p == 0) rscale1[v] = rm * (1.f / 127.f);
}

// ---------------------------------------------------------------------------
// K2: FUSED hat1 + fc_out-projection, MLP-batched gather:
//   Phase A: z = mean_17(q1 rows); l2 = log0(relu(exp0(z))) -> bf16 tile in LDS
//   Phase B: y = l2_tile @ W_out + b_out (MFMA), quantize per-row -> qy
// Loads issued in two register batches (8, then 9) so 8-17 VMEM ops stay in
// flight per lane; decode overlaps the second batch's latency.
// ---------------------------------------------------------------------------
__global__ __launch_bounds__(256, 4) void k_hat1_fc(
    const uchar* __restrict__ q1, const float* __restrict__ rscale1,
    const int* __restrict__ src,
    const ushort* __restrict__ Wo_t, const float* __restrict__ b_out,
    uchar* __restrict__ qy, float* __restrict__ rscale_y)
{
    __shared__ int lsrc[256];
    __shared__ ushort T[16][264];        // 16 l2 rows, +8 pad
    __shared__ float smaxq[4][16];

    const int tid = threadIdx.x;
    const int gi  = tid >> 4;           // node within block
    const int p   = tid & 15;           // 16-col chunk
    const int vb  = blockIdx.x * 16;
    const int v   = vb + gi;
    const int base = gi << 4;

    lsrc[tid] = src[(size_t)vb * DEG + tid];
    __syncthreads();

    // ---- phase A: batched gather (rows 0-7, then 8-15 + self) ----
    uint4 ra[8]; float sa[8];
    #pragma unroll
    for (int j = 0; j < 8; ++j) {
        const int s = lsrc[base | j];
        ra[j] = *(const uint4*)(q1 + ((size_t)s << 8) + p * 16);
        sa[j] = rscale1[s];
    }
    uint4 rb[9]; float sb[9];
    #pragma unroll
    for (int j = 0; j < 8; ++j) {
        const int s = lsrc[base | (8 + j)];
        rb[j] = *(const uint4*)(q1 + ((size_t)s << 8) + p * 16);
        sb[j] = rscale1[s];
    }
    rb[8] = *(const uint4*)(q1 + ((size_t)v << 8) + p * 16);
    sb[8] = rscale1[v];

    float acc[16];
    #pragma unroll
    for (int i = 0; i < 16; i++) acc[i] = 0.f;
    float srs = 0.f;
    #pragma unroll
    for (int j = 0; j < 8; ++j) { srs += sa[j]; acc16(acc, ra[j], sa[j]); }
    #pragma unroll
    for (int j = 0; j < 9; ++j) { srs += sb[j]; acc16(acc, rb[j], sb[j]); }

    const float inv = 1.f / (float)(DEG + 1);
    const float bias = 128.f * srs;
    float rz[16], ss = 0.f, ssp = 0.f;
    #pragma unroll
    for (int i = 0; i < 16; i++) {
        float z = (acc[i] - bias) * inv;
        ss += z * z;
        rz[i] = fmaxf(z, 0.f);
        ssp += rz[i] * rz[i];
    }
    ss  = red16_sum(ss);
    ssp = red16_sum(ssp);

    float se = tanh_over_x(fmaxf(sqrtf(ss), EPSF));
    float nh = se * sqrtf(ssp);
    float nc = fminf(fmaxf(nh, EPSF), 1.f - EPSF);
    float c  = atanh_over_x(nc) * se;

    uint4 o1, o2;
    o1.x = pack2(c * rz[0],  c * rz[1]);
    o1.y = pack2(c * rz[2],  c * rz[3]);
    o1.z = pack2(c * rz[4],  c * rz[5]);
    o1.w = pack2(c * rz[6],  c * rz[7]);
    o2.x = pack2(c * rz[8],  c * rz[9]);
    o2.y = pack2(c * rz[10], c * rz[11]);
    o2.z = pack2(c * rz[12], c * rz[13]);
    o2.w = pack2(c * rz[14], c * rz[15]);
    *(uint4*)&T[gi][p * 16]     = o1;
    *(uint4*)&T[gi][p * 16 + 8] = o2;
    __syncthreads();

    // ---- phase B: y = T @ W_out + b_out, quantize -> qy ----
    const int lane = tid & 63;
    const int w    = tid >> 6;
    const int l15  = lane & 15;          // node
    const int lhi  = lane >> 4;

    f32x4 facc[2];
    facc[0] = (f32x4){0.f, 0.f, 0.f, 0.f};
    facc[1] = (f32x4){0.f, 0.f, 0.f, 0.f};

    const ushort* Wp = Wo_t + (size_t)(w * 2 * 16 + l15) * 256 + lhi * 8;

    for (int kk = 0; kk < 8; ++kk) {
        bf16x8 f = *(const bf16x8*)&T[l15][kk * 32 + lhi * 8];
        #pragma unroll
        for (int nf = 0; nf < 2; ++nf) {
            bf16x8 wv = *(const bf16x8*)(Wp + (size_t)nf * 16 * 256 + kk * 32);
            facc[nf] = __builtin_amdgcn_mfma_f32_16x16x32_bf16(wv, f, facc[nf], 0, 0, 0);
        }
    }

    float lm = 0.f;
    #pragma unroll
    for (int nf = 0; nf < 2; ++nf) {
        float4 bb = *(const float4*)&b_out[(w * 2 + nf) * 16 + lhi * 4];
        facc[nf][0] += bb.x; facc[nf][1] += bb.y;
        facc[nf][2] += bb.z; facc[nf][3] += bb.w;
        lm = fmaxf(lm, fmaxf(fmaxf(fabsf(facc[nf][0]), fabsf(facc[nf][1])),
                             fmaxf(fabsf(facc[nf][2]), fabsf(facc[nf][3]))));
    }
    lm = pl16_max(lm);
    lm = pl32_max(lm);
    if (lhi == 0) smaxq[w][l15] = lm;
    __syncthreads();

    float rm = fmaxf(fmaxf(smaxq[0][l15], smaxq[1][l15]),
                     fmaxf(smaxq[2][l15], smaxq[3][l15]));
    rm = fmaxf(rm, 1e-20f);
    const float qs = __fdividef(127.f, rm);
    const int node = vb + l15;

    #pragma unroll
    for (int nf = 0; nf < 2; ++nf) {
        uint b0 = (uint)(int)rintf(fmaf(facc[nf][0], qs, 128.f));
        uint b1 = (uint)(int)rintf(fmaf(facc[nf][1], qs, 128.f));
        uint b2 = (uint)(int)rintf(fmaf(facc[nf][2], qs, 128.f));
        uint b3 = (uint)(int)rintf(fmaf(facc[nf][3], qs, 128.f));
        *(uint*)&qy[(size_t)node * 128 + (w * 2 + nf) * 16 + lhi * 4] =
            b0 | (b1 << 8) | (b2 << 16) | (b3 << 24);
    }
    if (tid < 16) rscale_y[vb + tid] = rm * (1.f / 127.f);
}

// ---------------------------------------------------------------------------
// K3: out = exp0(mean_17(qy rows))   (128 B rows, biased u8)
// 16-lane group per node, lane-private accs; all 17 loads issued up front.
// ---------------------------------------------------------------------------
__global__ __launch_bounds__(256, 6) void k_hat2_q(
    const uchar* __restrict__ qy, const float* __restrict__ rscale_y,
    const int* __restrict__ src, float* __restrict__ out)
{
    __shared__ int lsrc[256];
    const int tid = threadIdx.x;
    const int gi  = tid >> 4;
    const int p   = tid & 15;           // 8 B chunk within 128 B row
    const int vb  = blockIdx.x * 16;
    const int v   = vb + gi;
    const int base = gi << 4;

    lsrc[tid] = src[(size_t)vb * DEG + tid];
    __syncthreads();

    uint2 r[17]; float sv[17];
    #pragma unroll
    for (int j = 0; j < 16; ++j) {
        const int s = lsrc[base | j];
        r[j] = *(const uint2*)(qy + ((size_t)s << 7) + p * 8);
        sv[j] = rscale_y[s];
    }
    r[16] = *(const uint2*)(qy + ((size_t)v << 7) + p * 8);
    sv[16] = rscale_y[v];

    float acc[8];
    #pragma unroll
    for (int i = 0; i < 8; i++) acc[i] = 0.f;
    float srs = 0.f;
    #pragma unroll
    for (int j = 0; j < 17; ++j) {
        srs += sv[j];
        acc4(acc + 0, r[j].x, sv[j]);
        acc4(acc + 4, r[j].y, sv[j]);
    }

    const float inv = 1.f / (float)(DEG + 1);
    const float bias = 128.f * srs;
    float z[8], ss = 0.f;
    #pragma unroll
    for (int i = 0; i < 8; i++) {
        z[i] = (acc[i] - bias) * inv;
        ss += z[i] * z[i];
    }
    ss = red16_sum(ss);

    float se = tanh_over_x(fmaxf(sqrtf(ss), EPSF));

    float4 o0, o1;
    o0.x = se * z[0]; o0.y = se * z[1]; o0.z = se * z[2]; o0.w = se * z[3];
    o1.x = se * z[4]; o1.y = se * z[5]; o1.z = se * z[6]; o1.w = se * z[7];
    float* row = out + (size_t)v * 128 + p * 8;
    *(float4*)row = o0;
    *(float4*)(row + 4) = o1;
}

extern "C" void kernel_launch(void* const* d_in, const int* in_sizes, int n_in,
                              void* d_out, int out_size, void* d_ws, size_t ws_size,
                              hipStream_t stream) {
    const int*   x     = (const int*)  d_in[0];
    const float* emb0  = (const float*)d_in[1];
    const float* emb1  = (const float*)d_in[2];
    const float* emb2  = (const float*)d_in[3];
    const float* W_in  = (const float*)d_in[4];
    const float* b_in  = (const float*)d_in[5];
    const float* W_out = (const float*)d_in[6];
    const float* b_out = (const float*)d_in[7];
    const int*   src0  = (const int*)  d_in[8];
    const int*   src1  = (const int*)  d_in[10];
    float* out = (float*)d_out;

    uchar*  q1       = (uchar*)d_ws;                            // 12.8 MB
    uchar*  qy       = q1 + (size_t)N_NODES * 256;              // 6.4 MB
    float*  rscale1  = (float*)(qy + (size_t)N_NODES * 128);    // 200 KB
    float*  rscale_y = rscale1 + N_NODES;                       // 200 KB
    ushort* W_t      = (ushort*)(rscale_y + N_NODES);           // 128 KB
    ushort* Wo_t     = W_t + 256 * 256;                         // 64 KB
    float*  P0       = (float*)(Wo_t + 128 * 256);              // 1 MB (1024 rows)
    float*  P1       = P0 + 1024 * 256;                         // 1 MB
    float*  P2       = P1 + 1024 * 256;                         // 1 MB

    k_prep<<<384, 256, 0, stream>>>(W_in, W_out, W_t, Wo_t);
    k_projtab<<<189, 256, 0, stream>>>(emb0, emb1, emb2, W_t, P0, P1, P2);
    k_encode_gather<<<N_NODES / 16, 256, 0, stream>>>(x, P0, P1, P2, b_in, q1, rscale1);
    k_hat1_fc<<<N_NODES / 16, 256, 0, stream>>>(q1, rscale1, src0, Wo_t, b_out, qy, rscale_y);
    k_hat2_q<<<N_NODES / 16, 256, 0, stream>>>(qy, rscale_y, src1, out);
}